// Round 1
// baseline (1784.269 us; speedup 1.0000x reference)
//
#include <hip/hip_runtime.h>
#include <math.h>

#define NN 14            // nodes per graph
#define HH 4             // heads
#define CC 64            // channels per head
#define FF 128           // input features
#define EE 182           // edges per graph (before self-loops)
#define TE (EE + NN)     // 196 total edges
#define HC (HH * CC)     // 256

// One GAT layer, everything in LDS. F = input feature dim (128 or 64).
// Block = 256 threads. Wg is [F, 256] row-major in global (L2-resident).
template<int F>
__device__ __forceinline__ void gat_layer(int t,
    const float* __restrict__ Wg,
    const float* __restrict__ asg,     // [4,64]
    const float* __restrict__ adg,     // [4,64]
    const float* __restrict__ bias,    // [64]
    int do_relu,
    const float* xin,                  // LDS [NN*F]
    float* hs,                         // LDS [NN*256]
    float* als, float* ald,            // LDS [NN*HH] each
    float* alpha_s,                    // LDS [TE*HH]
    const int* esrc, const int* edst,  // LDS [TE]
    const int* scnt,                   // LDS [NN+1] segment starts (sorted by dst)
    const int* order,                  // LDS [TE] edge ids sorted by dst
    float* msh, float* dsh,            // LDS [NN*HH]
    float* outp,                       // LDS [HH*NN*CC] per-head partials
    float* xout)                       // LDS [NN*CC]
{
    // ---- h = x @ W : thread t owns column t, all 14 rows ----
    {
        float acc[NN];
        #pragma unroll
        for (int n = 0; n < NN; n++) acc[n] = 0.f;
        for (int k = 0; k < F; k += 4) {
            float w0 = Wg[(k+0)*HC + t];
            float w1 = Wg[(k+1)*HC + t];
            float w2 = Wg[(k+2)*HC + t];
            float w3 = Wg[(k+3)*HC + t];
            #pragma unroll
            for (int n = 0; n < NN; n++) {
                float4 xv = *(const float4*)(xin + n*F + k);   // wave-uniform broadcast
                acc[n] += xv.x*w0 + xv.y*w1 + xv.z*w2 + xv.w*w3;
            }
        }
        #pragma unroll
        for (int n = 0; n < NN; n++) hs[n*HC + t] = acc[n];
    }
    __syncthreads();

    // ---- attention coefficients al_src/al_dst : 112 threads, 64-len dots ----
    if (t < NN*HH*2) {
        int which = t & 1;
        int nh = t >> 1;            // 0..55
        int n = nh >> 2, h = nh & 3;
        const float* av = (which ? adg : asg) + h*CC;
        const float* hv = hs + n*HC + h*CC;
        float a = 0.f;
        #pragma unroll 8
        for (int c = 0; c < CC; c++) a += hv[c] * av[c];
        if (which) ald[nh] = a; else als[nh] = a;
    }
    __syncthreads();

    // ---- per-edge logits with leaky-relu ----
    for (int i = t; i < TE*HH; i += 256) {
        int e = i >> 2, h = i & 3;
        float v = als[esrc[e]*HH + h] + ald[edst[e]*HH + h];
        alpha_s[i] = (v > 0.f) ? v : 0.2f * v;
    }
    __syncthreads();

    // ---- segment softmax stats per (dst,h): 56 threads scan sorted segments ----
    if (t < NN*HH) {
        int n = t >> 2, h = t & 3;
        int s0 = scnt[n], s1 = scnt[n+1];
        float m = -1e30f;
        for (int j = s0; j < s1; j++) m = fmaxf(m, alpha_s[order[j]*HH + h]);
        float den = 0.f;
        for (int j = s0; j < s1; j++) den += __expf(alpha_s[order[j]*HH + h] - m);
        msh[t] = m; dsh[t] = den;
    }
    __syncthreads();

    // ---- normalize alpha ----
    for (int i = t; i < TE*HH; i += 256) {
        int e = i >> 2, h = i & 3;
        int d = edst[e];
        alpha_s[i] = __expf(alpha_s[i] - msh[d*HH + h]) / dsh[d*HH + h];
    }
    __syncthreads();

    // ---- aggregate: thread = (head = t>>6, c = t&63); sorted segments per dst ----
    {
        int h = t >> 6, c = t & 63;
        for (int n = 0; n < NN; n++) {
            float acc = 0.f;
            int s0 = scnt[n], s1 = scnt[n+1];
            for (int j = s0; j < s1; j++) {
                int e = order[j];
                acc += alpha_s[e*HH + h] * hs[esrc[e]*HC + h*CC + c];
            }
            outp[(h*NN + n)*CC + c] = acc;
        }
    }
    __syncthreads();

    // ---- mean over heads + bias (+ relu) ----
    for (int i = t; i < NN*CC; i += 256) {
        int n = i >> 6, c = i & 63;
        float v = 0.25f * (outp[(0*NN+n)*CC + c] + outp[(1*NN+n)*CC + c] +
                           outp[(2*NN+n)*CC + c] + outp[(3*NN+n)*CC + c]) + bias[c];
        if (do_relu) v = fmaxf(v, 0.f);
        xout[i] = v;
    }
    __syncthreads();
}

__global__ __launch_bounds__(256) void gat_fused(
    const float* __restrict__ feature,   // [B,14,128]
    const int*   __restrict__ edge_list, // [B,182,2] int32
    const float* __restrict__ W1, const float* __restrict__ as1,
    const float* __restrict__ ad1, const float* __restrict__ b1,
    const float* __restrict__ W2, const float* __restrict__ as2,
    const float* __restrict__ ad2, const float* __restrict__ b2,
    const float* __restrict__ Wl,        // [896,32]
    const float* __restrict__ bl,        // [32]
    const float* __restrict__ Wp,        // [32]
    const float* __restrict__ bp,        // [1]
    float* __restrict__ out)             // [B]
{
    const int g = blockIdx.x;
    const int t = threadIdx.x;

    __shared__ __align__(16) float xs[NN*FF];       // 7168 B
    __shared__ __align__(16) float hs[NN*HC];       // 14336 B
    __shared__ float als[NN*HH], ald[NN*HH];        // 224+224 B
    __shared__ float alpha_s[TE*HH];                // 3136 B
    __shared__ int   esrc[TE], edst[TE];            // 1568 B
    __shared__ int   scnt[NN+1], scur[NN];          // 116 B
    __shared__ int   order[TE];                     // 784 B
    __shared__ float msh[NN*HH], dsh[NN*HH];        // 448 B
    __shared__ __align__(16) float outp[HH*NN*CC];  // 14336 B
    __shared__ __align__(16) float x2s[NN*CC];      // 3584 B
    __shared__ float zs[8*32];                      // 1024 B

    // ---- stage input features ----
    const float* xg = feature + (size_t)g * NN * FF;
    for (int i = t; i < NN*FF; i += 256) xs[i] = xg[i];

    // ---- load edges (+self loops) and counting-sort by dst (reused both layers) ----
    if (t < NN) scur[t] = 0;
    __syncthreads();
    if (t < TE) {
        int s, d;
        if (t < EE) {
            int2 sd = *(const int2*)(edge_list + (size_t)g * EE * 2 + t * 2);
            s = sd.x; d = sd.y;
        } else {
            s = d = t - EE;     // self loops
        }
        esrc[t] = s; edst[t] = d;
        atomicAdd(&scur[d], 1);
    }
    __syncthreads();
    if (t == 0) {
        int run = 0;
        for (int i = 0; i < NN; i++) { scnt[i] = run; run += scur[i]; }
        scnt[NN] = run;          // == TE
    }
    __syncthreads();
    if (t < NN) scur[t] = scnt[t];
    __syncthreads();
    if (t < TE) {
        int p = atomicAdd(&scur[edst[t]], 1);
        order[p] = t;
    }
    __syncthreads();

    // ---- layer 1 (relu) : xs -> x2s ----
    gat_layer<FF>(t, W1, as1, ad1, b1, 1, xs, hs, als, ald, alpha_s,
                  esrc, edst, scnt, order, msh, dsh, outp, x2s);
    // ---- layer 2 (no relu) : x2s -> x2s (safe: GEMM consumes xin before overwrite) ----
    gat_layer<CC>(t, W2, as2, ad2, b2, 0, x2s, hs, als, ald, alpha_s,
                  esrc, edst, scnt, order, msh, dsh, outp, x2s);

    // ---- head: z[j] = flatten(x2) @ Wl + bl ; p = z @ Wp + bp ; sigmoid ----
    {
        int j = t & 31, part = t >> 5;   // 8 partials of 112 elements each
        float acc = 0.f;
        int i0 = part * 112;
        for (int i = i0; i < i0 + 112; i++)
            acc += x2s[i] * Wl[i*32 + j];
        zs[part*32 + j] = acc;
    }
    __syncthreads();
    if (t < 32) {
        float z = bl[t];
        #pragma unroll
        for (int p = 0; p < 8; p++) z += zs[p*32 + t];
        zs[t] = z * Wp[t];
    }
    __syncthreads();
    if (t == 0) {
        float p = bp[0];
        #pragma unroll
        for (int j = 0; j < 32; j++) p += zs[j];
        out[g] = 1.f / (1.f + __expf(-p));
    }
}

extern "C" void kernel_launch(void* const* d_in, const int* in_sizes, int n_in,
                              void* d_out, int out_size, void* d_ws, size_t ws_size,
                              hipStream_t stream) {
    const float* feature = (const float*)d_in[0];
    const int*   edges   = (const int*)d_in[1];
    const float* W1  = (const float*)d_in[2];
    const float* as1 = (const float*)d_in[3];
    const float* ad1 = (const float*)d_in[4];
    const float* b1  = (const float*)d_in[5];
    const float* W2  = (const float*)d_in[6];
    const float* as2 = (const float*)d_in[7];
    const float* ad2 = (const float*)d_in[8];
    const float* b2  = (const float*)d_in[9];
    const float* Wl  = (const float*)d_in[10];
    const float* bl  = (const float*)d_in[11];
    const float* Wp  = (const float*)d_in[12];
    const float* bp  = (const float*)d_in[13];
    float* out = (float*)d_out;

    const int B = in_sizes[0] / (NN * FF);
    gat_fused<<<B, 256, 0, stream>>>(feature, edges, W1, as1, ad1, b1,
                                     W2, as2, ad2, b2, Wl, bl, Wp, bp, out);
}

// Round 2
// 1394.046 us; speedup vs baseline: 1.2799x; 1.2799x over previous
//
#include <hip/hip_runtime.h>

#define NN 14            // nodes per graph
#define HH 4             // heads
#define CC 64            // channels per head
#define FF 128           // input features
#define EE 182           // edges per graph (before self-loops)
#define TE (EE + NN)     // 196 total edges
#define HC (HH * CC)     // 256

typedef __attribute__((ext_vector_type(8))) short bf16x8;
typedef __attribute__((ext_vector_type(4))) float f32x4;

// float -> bf16 (RNE, finite inputs)
__device__ __forceinline__ unsigned short f2bf(float f) {
    unsigned u = __float_as_uint(f);
    unsigned r = (u + 0x7fffu + ((u >> 16) & 1u)) >> 16;
    return (unsigned short)r;
}
__device__ __forceinline__ float bflo(unsigned u) { return __uint_as_float(u << 16); }
__device__ __forceinline__ float bfhi(unsigned u) { return __uint_as_float(u & 0xffff0000u); }
__device__ __forceinline__ float bfs(short s) {
    return __uint_as_float(((unsigned)(unsigned short)s) << 16);
}

// ---------------------------------------------------------------------------
// Weight pre-pack kernel (runs every launch; d_ws is re-poisoned each call).
// wp1: W1 [128,256] -> B-frag order: idx = ((nt*4+kk)*64+lane)*8+j
//      value = W1[kk*32 + (lane>>4)*8 + j][nt*16 + (lane&15)]
// wp2: same with KK=2 (K=64)
// wlp: Wl [896,32] -> u32 pack of (row 2*i2, row 2*i2+1) at col j: wlp[i2*32+j]
// ---------------------------------------------------------------------------
__global__ void prep_pack(const float* __restrict__ W1, const float* __restrict__ W2,
                          const float* __restrict__ Wl,
                          short* __restrict__ wp1, short* __restrict__ wp2,
                          unsigned* __restrict__ wlp) {
    int gid = blockIdx.x * 256 + threadIdx.x;
    if (gid < 32768) {
        int j = gid & 7, L = (gid >> 3) & 63, kk = (gid >> 9) & 3, nt = gid >> 11;
        int k = kk * 32 + (L >> 4) * 8 + j, n = nt * 16 + (L & 15);
        wp1[gid] = (short)f2bf(W1[k * 256 + n]);
    } else if (gid < 49152) {
        int g2 = gid - 32768;
        int j = g2 & 7, L = (g2 >> 3) & 63, kk = (g2 >> 9) & 1, nt = g2 >> 10;
        int k = kk * 32 + (L >> 4) * 8 + j, n = nt * 16 + (L & 15);
        wp2[g2] = (short)f2bf(W2[k * 256 + n]);
    } else if (gid < 63488) {
        int o = gid - 49152;
        int j = o & 31, i2 = o >> 5;
        unsigned lo = f2bf(Wl[(2 * i2) * 32 + j]);
        unsigned hi = f2bf(Wl[(2 * i2 + 1) * 32 + j]);
        wlp[o] = lo | (hi << 16);
    }
}

// ---------------------------------------------------------------------------
// One GAT layer. KK = K/32 MFMA k-steps, AS = A-source row stride (bf16 units).
// hsb layout: packed bf16x2, row stride 132 u32 (=264 bf16, +8 pad -> bank rot 4).
// Wave w computes head w's 64 columns (N-tiles w*4 .. w*4+3).
// ---------------------------------------------------------------------------
template<int KK, int AS, bool RELU>
__device__ __forceinline__ void gat_layer(int t,
    const short* __restrict__ Asrc, const short* __restrict__ Wp,
    const float* __restrict__ asg, const float* __restrict__ adg,
    const float* __restrict__ bias,
    unsigned* hsb, float* alpha_s, float* als, float* ald,
    const int* esrc, const int* edst, const int* scnt, const int* order,
    float* msh, float* dsh, float* x2s, short* x2b)
{
    // zero the cross-head accumulation buffer (consumed-last in prev layer)
    for (int i = t; i < NN * CC; i += 256) x2s[i] = 0.f;

    // ---- GEMM h = A @ W via MFMA 16x16x32 bf16 ----
    {
        int wave = t >> 6, lane = t & 63;
        int m = lane & 15, q = lane >> 4;
        f32x4 acc[4];
        #pragma unroll
        for (int tl = 0; tl < 4; ++tl) acc[tl] = f32x4{0.f, 0.f, 0.f, 0.f};
        const short* Ab = Asrc + m * AS + q * 8;
        const bf16x8* Bp = (const bf16x8*)Wp;
        #pragma unroll
        for (int kk = 0; kk < KK; ++kk) {
            bf16x8 a = *(const bf16x8*)(Ab + kk * 32);
            #pragma unroll
            for (int tl = 0; tl < 4; ++tl) {
                bf16x8 b = Bp[(((wave * 4 + tl) * KK) + kk) * 64 + lane];
                acc[tl] = __builtin_amdgcn_mfma_f32_16x16x32_bf16(a, b, acc[tl], 0, 0, 0);
            }
        }
        // C layout: col = lane&15, row = (lane>>4)*4 + reg. Pack col-pairs via shfl.
        #pragma unroll
        for (int tl = 0; tl < 4; ++tl) {
            int cg = wave * 64 + tl * 16 + m;
            #pragma unroll
            for (int r = 0; r < 4; ++r) {
                float v = acc[tl][r];
                float pv = __shfl_xor(v, 1);
                if (!(lane & 1))
                    hsb[(q * 4 + r) * 132 + (cg >> 1)] =
                        (unsigned)f2bf(v) | ((unsigned)f2bf(pv) << 16);
            }
        }
    }
    __syncthreads();

    // ---- attention coefficients: 112 threads, 64-len bf16 dots ----
    if (t < NN * HH * 2) {
        int which = t & 1, nh = t >> 1;
        int n = nh >> 2, h = nh & 3;
        const float* av = (which ? adg : asg) + h * CC;
        const short* hp = (const short*)hsb + n * 264 + h * 64;
        float a = 0.f;
        #pragma unroll
        for (int b = 0; b < 8; ++b) {
            bf16x8 hv = *(const bf16x8*)(hp + b * 8);
            const float* ap = av + b * 8;
            a += bfs(hv[0]) * ap[0] + bfs(hv[1]) * ap[1] + bfs(hv[2]) * ap[2] +
                 bfs(hv[3]) * ap[3] + bfs(hv[4]) * ap[4] + bfs(hv[5]) * ap[5] +
                 bfs(hv[6]) * ap[6] + bfs(hv[7]) * ap[7];
        }
        if (which) ald[nh] = a; else als[nh] = a;
    }
    __syncthreads();

    // ---- per-edge logits + leaky-relu ----
    for (int i = t; i < TE * HH; i += 256) {
        int e = i >> 2, h = i & 3;
        float v = als[esrc[e] * HH + h] + ald[edst[e] * HH + h];
        alpha_s[i] = (v > 0.f) ? v : 0.2f * v;
    }
    __syncthreads();

    // ---- segment softmax stats per (dst,h) ----
    if (t < NN * HH) {
        int n = t >> 2, h = t & 3;
        int s0 = scnt[n], s1 = scnt[n + 1];
        float m = -1e30f;
        for (int j = s0; j < s1; j++) m = fmaxf(m, alpha_s[order[j] * HH + h]);
        float den = 0.f;
        for (int j = s0; j < s1; j++) den += __expf(alpha_s[order[j] * HH + h] - m);
        msh[t] = m; dsh[t] = den;
    }
    __syncthreads();

    // ---- normalize alpha ----
    for (int i = t; i < TE * HH; i += 256) {
        int e = i >> 2, h = i & 3;
        int d = edst[e];
        alpha_s[i] = __expf(alpha_s[i] - msh[d * HH + h]) / dsh[d * HH + h];
    }
    __syncthreads();

    // ---- aggregation: thread = (half = t>>7, h = (t>>5)&3, c2 = t&31) ----
    // reads hsb (2-way bank alias = free), accumulates cross-head via LDS atomics
    {
        int c2 = t & 31;
        int h = (t >> 5) & 3;
        int half = t >> 7;
        int n1 = half * 7 + 7;
        for (int n = half * 7; n < n1; ++n) {
            float a0 = 0.f, a1 = 0.f;
            int s0 = scnt[n], s1 = scnt[n + 1];
            for (int jj = s0; jj < s1; ++jj) {
                int e = order[jj];
                float al = alpha_s[e * 4 + h];
                unsigned hv = hsb[esrc[e] * 132 + h * 32 + c2];
                a0 += al * bflo(hv);
                a1 += al * bfhi(hv);
            }
            atomicAdd(&x2s[n * 64 + 2 * c2],     0.25f * a0);
            atomicAdd(&x2s[n * 64 + 2 * c2 + 1], 0.25f * a1);
        }
    }
    __syncthreads();

    // ---- bias (+relu) ; layer1 -> bf16 A-layout x2b ; layer2 -> fp32 x2s ----
    for (int i = t; i < NN * CC; i += 256) {
        int n = i >> 6, c = i & 63;
        float v = x2s[i] + bias[c];
        if (RELU) {
            v = fmaxf(v, 0.f);
            x2b[n * 72 + c] = (short)f2bf(v);
        } else {
            x2s[i] = v;
        }
    }
    __syncthreads();
}

__global__ __launch_bounds__(256, 4) void gat_fused(
    const float* __restrict__ feature,   // [B,14,128]
    const int*   __restrict__ edge_list, // [B,182,2] int32
    const float* __restrict__ as1, const float* __restrict__ ad1,
    const float* __restrict__ b1,
    const float* __restrict__ as2, const float* __restrict__ ad2,
    const float* __restrict__ b2,
    const float* __restrict__ bl,        // [32]
    const float* __restrict__ Wpred,     // [32]
    const float* __restrict__ bp,        // [1]
    const short* __restrict__ wp1,       // packed W1 B-frags (bf16)
    const short* __restrict__ wp2,       // packed W2 B-frags (bf16)
    const unsigned* __restrict__ wlp,    // packed Wl bf16 pairs
    float* __restrict__ out)             // [B]
{
    const int g = blockIdx.x;
    const int t = threadIdx.x;

    __shared__ __align__(16) short    xb[16 * 136];   // 4352 B  A-frag layer1 (stride 136)
    __shared__ __align__(16) unsigned hsb[16 * 132];  // 8448 B  h packed bf16x2 (stride 132 u32)
    __shared__ __align__(16) short    x2b[16 * 72];   // 2304 B  A-frag layer2 (stride 72)
    __shared__ float alpha_s[TE * HH];                // 3136 B
    __shared__ float als[NN * HH], ald[NN * HH];      // 448 B
    __shared__ int   esrc[TE], edst[TE], order[TE];   // 2352 B
    __shared__ int   scnt[NN + 1], scur[NN];          // 116 B
    __shared__ float msh[NN * HH], dsh[NN * HH];      // 448 B
    __shared__ __align__(16) float x2s[NN * CC];      // 3584 B
    __shared__ float zs[256];                         // 1024 B
    // total ~25.6 KB -> 6 blocks/CU (LDS-wise)

    // ---- zero A-frag pad rows 14,15 (read by MFMA as m=14,15) ----
    for (int i = t; i < 136; i += 256) ((unsigned*)xb)[952 + i] = 0;   // rows 14,15 of xb
    for (int i = t; i < 72;  i += 256) ((unsigned*)x2b)[504 + i] = 0;  // rows 14,15 of x2b

    // ---- stage input features as bf16 into A-frag layout ----
    const float* xg = feature + (size_t)g * NN * FF;
    for (int i4 = t; i4 < NN * FF / 4; i4 += 256) {    // 448 float4s
        float4 v = *(const float4*)(xg + i4 * 4);
        int n = i4 >> 5;            // (i4*4)/128
        int k = (i4 & 31) * 4;
        unsigned p0 = (unsigned)f2bf(v.x) | ((unsigned)f2bf(v.y) << 16);
        unsigned p1 = (unsigned)f2bf(v.z) | ((unsigned)f2bf(v.w) << 16);
        *(uint2*)(xb + n * 136 + k) = make_uint2(p0, p1);
    }

    // ---- load edges (+self loops) and counting-sort by dst (reused both layers) ----
    if (t < NN) scur[t] = 0;
    __syncthreads();
    if (t < TE) {
        int s, d;
        if (t < EE) {
            int2 sd = *(const int2*)(edge_list + (size_t)g * EE * 2 + t * 2);
            s = sd.x; d = sd.y;
        } else {
            s = d = t - EE;          // self loops
        }
        esrc[t] = s; edst[t] = d;
        atomicAdd(&scur[d], 1);
    }
    __syncthreads();
    if (t == 0) {
        int run = 0;
        for (int i = 0; i < NN; i++) { scnt[i] = run; run += scur[i]; }
        scnt[NN] = run;
    }
    __syncthreads();
    if (t < NN) scur[t] = scnt[t];
    __syncthreads();
    if (t < TE) {
        int p = atomicAdd(&scur[edst[t]], 1);
        order[p] = t;
    }
    __syncthreads();

    // ---- layer 1 (relu) : xb -> x2b ----
    gat_layer<4, 136, true >(t, xb,  wp1, as1, ad1, b1, hsb, alpha_s, als, ald,
                             esrc, edst, scnt, order, msh, dsh, x2s, x2b);
    // ---- layer 2 : x2b -> x2s ----
    gat_layer<2, 72,  false>(t, x2b, wp2, as2, ad2, b2, hsb, alpha_s, als, ald,
                             esrc, edst, scnt, order, msh, dsh, x2s, x2b);

    // ---- head: z = flat(x2) @ Wl + bl ; p = z @ Wpred + bp ; sigmoid ----
    {
        int j = t & 31, part = t >> 5;     // 8 parts x 56 row-pairs
        float acc = 0.f;
        int e2 = part * 56 + 56;
        for (int i2 = part * 56; i2 < e2; ++i2) {
            unsigned wv = wlp[i2 * 32 + j];
            float2 xv = *(const float2*)(x2s + 2 * i2);
            acc += xv.x * bflo(wv) + xv.y * bfhi(wv);
        }
        zs[t] = acc;
    }
    __syncthreads();
    if (t < 32) {
        float z = bl[t];
        #pragma unroll
        for (int p = 0; p < 8; ++p) z += zs[p * 32 + t];
        zs[t] = z * Wpred[t];
    }
    __syncthreads();
    if (t == 0) {
        float p = bp[0];
        #pragma unroll
        for (int j = 0; j < 32; ++j) p += zs[j];
        out[g] = 1.f / (1.f + __expf(-p));
    }
}

extern "C" void kernel_launch(void* const* d_in, const int* in_sizes, int n_in,
                              void* d_out, int out_size, void* d_ws, size_t ws_size,
                              hipStream_t stream) {
    const float* feature = (const float*)d_in[0];
    const int*   edges   = (const int*)d_in[1];
    const float* W1  = (const float*)d_in[2];
    const float* as1 = (const float*)d_in[3];
    const float* ad1 = (const float*)d_in[4];
    const float* b1  = (const float*)d_in[5];
    const float* W2  = (const float*)d_in[6];
    const float* as2 = (const float*)d_in[7];
    const float* ad2 = (const float*)d_in[8];
    const float* b2  = (const float*)d_in[9];
    const float* Wl  = (const float*)d_in[10];
    const float* bl  = (const float*)d_in[11];
    const float* Wp  = (const float*)d_in[12];
    const float* bp  = (const float*)d_in[13];
    float* out = (float*)d_out;

    short*    wp1 = (short*)d_ws;               // 32768 bf16
    short*    wp2 = wp1 + 32768;                // 16384 bf16
    unsigned* wlp = (unsigned*)(wp1 + 49152);   // 14336 u32 (offset 98304 B)

    prep_pack<<<248, 256, 0, stream>>>(W1, W2, Wl, wp1, wp2, wlp);

    const int B = in_sizes[0] / (NN * FF);
    gat_fused<<<B, 256, 0, stream>>>(feature, edges, as1, ad1, b1, as2, ad2, b2,
                                     bl, Wp, bp, wp1, wp2, wlp, out);
}

// Round 3
// 495.039 us; speedup vs baseline: 3.6043x; 2.8160x over previous
//
#include <hip/hip_runtime.h>

#define NN 14            // nodes per graph
#define HH 4             // heads
#define CC 64            // channels per head
#define FF 128           // input features
#define EE 182           // edges per graph (before self-loops)
#define TE (EE + NN)     // 196 total edges

typedef __attribute__((ext_vector_type(8))) short bf16x8;
typedef __attribute__((ext_vector_type(4))) float f32x4;

// float -> bf16 (RNE, finite inputs)
__device__ __forceinline__ unsigned f2bf(float f) {
    unsigned u = __float_as_uint(f);
    return (u + 0x7fffu + ((u >> 16) & 1u)) >> 16;
}
__device__ __forceinline__ float bflo(unsigned u) { return __uint_as_float(u << 16); }
__device__ __forceinline__ float bfhi(unsigned u) { return __uint_as_float(u & 0xffff0000u); }
__device__ __forceinline__ float bfs(short s) {
    return __uint_as_float(((unsigned)(unsigned short)s) << 16);
}

// ---------------------------------------------------------------------------
// Weight pre-pack (every launch; d_ws re-poisoned each call).
// wp1/wp2: W -> MFMA B-frag order: idx = ((nt*KK+kk)*64+L)*8+j,
//          value = W[kk*32+(L>>4)*8+j][nt*16+(L&15)]   (KK=4 for W1, 2 for W2)
// wlp:     Wl[896,32] -> u32 pack of rows (2i2, 2i2+1) at col j: wlp[i2*32+j]
// wal1/2:  combined attention vectors  w = W[:, h*64:h*64+64] @ a[h]
//          layout [which][h][K]  (which: 0=src 1=dst)
// ---------------------------------------------------------------------------
__global__ void prep_pack(const float* __restrict__ W1, const float* __restrict__ W2,
                          const float* __restrict__ Wl,
                          const float* __restrict__ as1, const float* __restrict__ ad1,
                          const float* __restrict__ as2, const float* __restrict__ ad2,
                          short* __restrict__ wp1, short* __restrict__ wp2,
                          unsigned* __restrict__ wlp,
                          float* __restrict__ wal1, float* __restrict__ wal2) {
    int gid = blockIdx.x * 256 + threadIdx.x;
    if (gid < 32768) {
        int j = gid & 7, L = (gid >> 3) & 63, kk = (gid >> 9) & 3, nt = gid >> 11;
        int k = kk * 32 + (L >> 4) * 8 + j, n = nt * 16 + (L & 15);
        wp1[gid] = (short)f2bf(W1[k * 256 + n]);
    } else if (gid < 49152) {
        int g2 = gid - 32768;
        int j = g2 & 7, L = (g2 >> 3) & 63, kk = (g2 >> 9) & 1, nt = g2 >> 10;
        int k = kk * 32 + (L >> 4) * 8 + j, n = nt * 16 + (L & 15);
        wp2[g2] = (short)f2bf(W2[k * 256 + n]);
    } else if (gid < 63488) {
        int o = gid - 49152;
        int j = o & 31, i2 = o >> 5;
        wlp[o] = f2bf(Wl[(2 * i2) * 32 + j]) | (f2bf(Wl[(2 * i2 + 1) * 32 + j]) << 16);
    } else if (gid < 64512) {
        int o = gid - 63488;                    // which*512 + h*128 + k
        int k = o & 127, h = (o >> 7) & 3, which = o >> 9;
        const float* av = (which ? ad1 : as1) + h * 64;
        const float* wr = W1 + k * 256 + h * 64;
        float acc = 0.f;
        for (int c = 0; c < 64; ++c) acc += wr[c] * av[c];
        wal1[o] = acc;
    } else if (gid < 65024) {
        int o = gid - 64512;                    // which*256 + h*64 + k
        int k = o & 63, h = (o >> 6) & 3, which = o >> 8;
        const float* av = (which ? ad2 : as2) + h * 64;
        const float* wr = W2 + k * 256 + h * 64;
        float acc = 0.f;
        for (int c = 0; c < 64; ++c) acc += wr[c] * av[c];
        wal2[o] = acc;
    }
}

// ---------------------------------------------------------------------------
// One GAT layer, 4 barriers.
// A-frag src Ab_u: bf16 rows, u32 row stride AS (strides ≡4 mod 32 -> bank-uniform).
// hsTT[c][k]: c=within-head channel (64 rows, stride 36 u32), k=(head*16+src) bf16.
// Pd[16][68] fp32 dense exp-scatter (dst x (head*16+src)).
// aT[16][36u32]: bf16 A operand for agg GEMM = 0.25*alpha.
// ---------------------------------------------------------------------------
template<int KK, bool RELU>
__device__ __forceinline__ void gat_layer(int t, int es, int ed, bool has_edge,
    const unsigned* Ab_u, int AS,
    const short* __restrict__ Wp, const float* __restrict__ wal,
    const float* __restrict__ bias,
    unsigned* hsTT, float* Pd, unsigned* aT, float* als, float* ald,
    unsigned* x2b, float* x2s)
{
    const int wave = t >> 6, lane = t & 63, m = lane & 15, q = lane >> 4;
    constexpr int K = KK * 32;

    // ======== Stage A: zero Pd ; attention dots (from input!) ; GEMM h=A@W ====
    for (int i = t; i < 16 * 68; i += 256) Pd[i] = 0.f;

    if (t < 224) {                       // 224 thr: (nh, which, half) split dots
        int half = t & 1, which = (t >> 1) & 1, nh = t >> 2;
        int n = nh >> 2, h = nh & 3;
        const short* xr = (const short*)(Ab_u + n * AS) + half * (K / 2);
        const float* wv = wal + (which * 4 + h) * K + half * (K / 2);
        float a = 0.f;
        #pragma unroll
        for (int b8 = 0; b8 < K / 16; ++b8) {
            bf16x8 xv = *(const bf16x8*)(xr + b8 * 8);
            float4 wa = *(const float4*)(wv + b8 * 8);
            float4 wb = *(const float4*)(wv + b8 * 8 + 4);
            a += bfs(xv[0]) * wa.x + bfs(xv[1]) * wa.y + bfs(xv[2]) * wa.z +
                 bfs(xv[3]) * wa.w + bfs(xv[4]) * wb.x + bfs(xv[5]) * wb.y +
                 bfs(xv[6]) * wb.z + bfs(xv[7]) * wb.w;
        }
        a += __shfl_xor(a, 1);
        if (!half) { if (which) ald[nh] = a; else als[nh] = a; }
    }

    {   // GEMM: wave w -> channels w*64..w*64+63 (head w), rows = nodes
        f32x4 acc[4];
        #pragma unroll
        for (int tl = 0; tl < 4; ++tl) acc[tl] = f32x4{0.f, 0.f, 0.f, 0.f};
        const short* Ar = (const short*)(Ab_u + m * AS) + q * 8;
        const bf16x8* Bp = (const bf16x8*)Wp;
        #pragma unroll
        for (int kk = 0; kk < KK; ++kk) {
            bf16x8 a = *(const bf16x8*)(Ar + kk * 32);
            #pragma unroll
            for (int tl = 0; tl < 4; ++tl) {
                bf16x8 b = Bp[((wave * 4 + tl) * KK + kk) * 64 + lane];
                acc[tl] = __builtin_amdgcn_mfma_f32_16x16x32_bf16(a, b, acc[tl], 0, 0, 0);
            }
        }
        // C: col=m (channel within tile), row=q*4+r (node). Write transposed:
        // hsTT[c=tl*16+m][k=wave*16+q*4+r] -- 4 consecutive k per lane -> 2 u32.
        #pragma unroll
        for (int tl = 0; tl < 4; ++tl) {
            unsigned* wp_ = hsTT + (tl * 16 + m) * 36 + wave * 8 + q * 2;
            wp_[0] = f2bf(acc[tl][0]) | (f2bf(acc[tl][1]) << 16);
            wp_[1] = f2bf(acc[tl][2]) | (f2bf(acc[tl][3]) << 16);
        }
    }
    __syncthreads();

    // ======== Stage B: per-edge leaky+exp, dense scatter (no max: logits < ~10)
    if (has_edge) {
        float4 a4 = *(const float4*)(als + es * 4);
        float4 d4 = *(const float4*)(ald + ed * 4);
        float l0 = a4.x + d4.x; l0 = (l0 > 0.f) ? l0 : 0.2f * l0;
        float l1 = a4.y + d4.y; l1 = (l1 > 0.f) ? l1 : 0.2f * l1;
        float l2 = a4.z + d4.z; l2 = (l2 > 0.f) ? l2 : 0.2f * l2;
        float l3 = a4.w + d4.w; l3 = (l3 > 0.f) ? l3 : 0.2f * l3;
        float* pr = Pd + ed * 68 + es;
        atomicAdd(pr +  0, __expf(l0));
        atomicAdd(pr + 16, __expf(l1));
        atomicAdd(pr + 32, __expf(l2));
        atomicAdd(pr + 48, __expf(l3));
    }
    __syncthreads();

    // ======== Stage C: rowsum16 = softmax denom; pack 0.25*alpha -> bf16 aT ====
    if (t < 56) {
        int n = t >> 2, h = t & 3;
        const float* pr = Pd + n * 68 + h * 16;
        float4 p0 = *(const float4*)pr,       p1 = *(const float4*)(pr + 4);
        float4 p2 = *(const float4*)(pr + 8), p3 = *(const float4*)(pr + 12);
        float s = p0.x + p0.y + p0.z + p0.w + p1.x + p1.y + p1.z + p1.w +
                  p2.x + p2.y + p2.z + p2.w + p3.x + p3.y + p3.z + p3.w;
        float inv = 0.25f / s;
        unsigned* ow = aT + n * 36 + h * 8;
        ow[0] = f2bf(p0.x * inv) | (f2bf(p0.y * inv) << 16);
        ow[1] = f2bf(p0.z * inv) | (f2bf(p0.w * inv) << 16);
        ow[2] = f2bf(p1.x * inv) | (f2bf(p1.y * inv) << 16);
        ow[3] = f2bf(p1.z * inv) | (f2bf(p1.w * inv) << 16);
        ow[4] = f2bf(p2.x * inv) | (f2bf(p2.y * inv) << 16);
        ow[5] = f2bf(p2.z * inv) | (f2bf(p2.w * inv) << 16);
        ow[6] = f2bf(p3.x * inv) | (f2bf(p3.y * inv) << 16);
        ow[7] = f2bf(p3.z * inv) | (f2bf(p3.w * inv) << 16);
    }
    __syncthreads();

    // ======== Stage D: agg GEMM C[n][c] = (0.25*alpha) @ hsTT ; bias(+relu) ====
    {
        f32x4 acc = f32x4{0.f, 0.f, 0.f, 0.f};
        const short* Ar = (const short*)aT + m * 72 + q * 8;
        const short* Br = (const short*)hsTT + (wave * 16 + m) * 72 + q * 8;
        #pragma unroll
        for (int kk = 0; kk < 2; ++kk)
            acc = __builtin_amdgcn_mfma_f32_16x16x32_bf16(
                *(const bf16x8*)(Ar + kk * 32), *(const bf16x8*)(Br + kk * 32),
                acc, 0, 0, 0);
        float bb = bias[wave * 16 + m];
        #pragma unroll
        for (int r = 0; r < 4; ++r) {
            int n = q * 4 + r;
            float v = acc[r] + bb;
            if (RELU) {
                v = fmaxf(v, 0.f);
                if (n >= NN) v = 0.f;          // keep pad rows finite-zero
                float pv = __shfl_xor(v, 1);
                if (!(m & 1))
                    x2b[n * 36 + wave * 8 + (m >> 1)] = f2bf(v) | (f2bf(pv) << 16);
            } else {
                float pv = __shfl_xor(v, 1);
                if (!(m & 1) && n < NN)
                    *(float2*)(x2s + n * 64 + wave * 16 + m) = make_float2(v, pv);
            }
        }
    }
    __syncthreads();
}

__global__ __launch_bounds__(256, 6) void gat_fused(
    const float* __restrict__ feature,   // [B,14,128]
    const int*   __restrict__ edge_list, // [B,182,2] int32
    const float* __restrict__ b1, const float* __restrict__ b2,
    const float* __restrict__ bl,        // [32]
    const float* __restrict__ Wpred,     // [32]
    const float* __restrict__ bp,        // [1]
    const short* __restrict__ wp1, const short* __restrict__ wp2,
    const unsigned* __restrict__ wlp,
    const float* __restrict__ wal1, const float* __restrict__ wal2,
    float* __restrict__ out)             // [B]
{
    const int g = blockIdx.x;
    const int t = threadIdx.x;

    __shared__ __align__(16) unsigned u_pool[1152];   // xb[16*68] U (x2s[896]+zs[256])
    __shared__ __align__(16) unsigned hsTT[64 * 36];  // 9216 B
    __shared__ __align__(16) unsigned x2b[16 * 36];   // 2304 B
    __shared__ __align__(16) float    Pd[16 * 68];    // 4352 B
    __shared__ __align__(16) unsigned aT[16 * 36];    // 2304 B
    __shared__ __align__(16) float    als[56];
    __shared__ __align__(16) float    ald[56];
    // total 23232 B -> 7 blocks/CU by LDS

    unsigned* xb = u_pool;
    float* x2s = (float*)u_pool;
    float* zs  = (float*)(u_pool + 896);

    // ---- edges in registers: one per thread ----
    int es = 0, ed = 0;
    const bool has_edge = (t < TE);
    if (t < EE) {
        int2 sd = *(const int2*)(edge_list + (size_t)g * EE * 2 + t * 2);
        es = sd.x; ed = sd.y;
    } else if (t < TE) {
        es = ed = t - EE;                 // self loops
    }

    // ---- stage features -> bf16 A-frag rows (stride 68 u32), zero pad rows ----
    const float* xg = feature + (size_t)g * NN * FF;
    for (int i4 = t; i4 < 448; i4 += 256) {
        float4 v = *(const float4*)(xg + i4 * 4);
        unsigned p0 = f2bf(v.x) | (f2bf(v.y) << 16);
        unsigned p1 = f2bf(v.z) | (f2bf(v.w) << 16);
        *(uint2*)(xb + (i4 >> 5) * 68 + (i4 & 31) * 2) = make_uint2(p0, p1);
    }
    for (int i = t; i < 2 * 68; i += 256) xb[14 * 68 + i] = 0;
    __syncthreads();

    // ---- layer 1 (relu) : xb -> x2b ----
    gat_layer<4, true >(t, es, ed, has_edge, xb, 68, wp1, wal1, b1,
                        hsTT, Pd, aT, als, ald, x2b, x2s);
    // ---- layer 2 : x2b -> x2s ----
    gat_layer<2, false>(t, es, ed, has_edge, x2b, 36, wp2, wal2, b2,
                        hsTT, Pd, aT, als, ald, x2b, x2s);

    // ---- head: z = flat(x2) @ Wl + bl ; p = z @ Wpred + bp ; sigmoid ----
    {
        int j = t & 31, part = t >> 5;     // 8 parts x 56 row-pairs
        const unsigned* wl = wlp + part * 56 * 32 + j;
        const float* xr = x2s + part * 112;
        float acc = 0.f;
        #pragma unroll 4
        for (int i2 = 0; i2 < 56; ++i2) {
            unsigned wv = wl[i2 * 32];
            float2 xv = *(const float2*)(xr + 2 * i2);
            acc += xv.x * bflo(wv) + xv.y * bfhi(wv);
        }
        zs[t] = acc;
    }
    __syncthreads();
    if (t < 32) {
        float z = bl[t];
        #pragma unroll
        for (int p = 0; p < 8; ++p) z += zs[p * 32 + t];
        zs[t] = z * Wpred[t];
    }
    __syncthreads();
    if (t == 0) {
        float p = bp[0];
        #pragma unroll
        for (int j = 0; j < 32; ++j) p += zs[j];
        out[g] = 1.f / (1.f + __expf(-p));
    }
}

extern "C" void kernel_launch(void* const* d_in, const int* in_sizes, int n_in,
                              void* d_out, int out_size, void* d_ws, size_t ws_size,
                              hipStream_t stream) {
    const float* feature = (const float*)d_in[0];
    const int*   edges   = (const int*)d_in[1];
    const float* W1  = (const float*)d_in[2];
    const float* as1 = (const float*)d_in[3];
    const float* ad1 = (const float*)d_in[4];
    const float* b1  = (const float*)d_in[5];
    const float* W2  = (const float*)d_in[6];
    const float* as2 = (const float*)d_in[7];
    const float* ad2 = (const float*)d_in[8];
    const float* b2  = (const float*)d_in[9];
    const float* Wl  = (const float*)d_in[10];
    const float* bl  = (const float*)d_in[11];
    const float* Wp  = (const float*)d_in[12];
    const float* bp  = (const float*)d_in[13];
    float* out = (float*)d_out;

    short*    wp1  = (short*)d_ws;               // 32768 bf16
    short*    wp2  = wp1 + 32768;                // 16384 bf16
    unsigned* wlp  = (unsigned*)(wp1 + 49152);   // 14336 u32
    float*    wal1 = (float*)(wlp + 14336);      // 1024 f32
    float*    wal2 = wal1 + 1024;                // 512 f32

    prep_pack<<<254, 256, 0, stream>>>(W1, W2, Wl, as1, ad1, as2, ad2,
                                       wp1, wp2, wlp, wal1, wal2);

    const int B = in_sizes[0] / (NN * FF);
    gat_fused<<<B, 256, 0, stream>>>(feature, edges, b1, b2, bl, Wp, bp,
                                     wp1, wp2, wlp, wal1, wal2, out);
}

// Round 4
// 315.412 us; speedup vs baseline: 5.6569x; 1.5695x over previous
//
#include <hip/hip_runtime.h>

#define NN 14
#define HH 4
#define CC 64
#define FF 128
#define EE 182

typedef __attribute__((ext_vector_type(8))) short bf16x8;
typedef __attribute__((ext_vector_type(4))) float f32x4;
typedef __attribute__((ext_vector_type(4))) unsigned u32x4;

__device__ __forceinline__ unsigned f2bf(float f) {
    unsigned u = __float_as_uint(f);
    return (u + 0x7fffu + ((u >> 16) & 1u)) >> 16;
}
__device__ __forceinline__ bf16x8 mk8(unsigned a, unsigned b, unsigned c, unsigned d) {
    u32x4 u = {a, b, c, d};
    return __builtin_bit_cast(bf16x8, u);
}

// ---------------------------------------------------------------------------
// Weight pre-pack (every launch; d_ws re-poisoned each call).
// wp1/wp2 : W -> MFMA B-frag order: idx = ((tile*KK+kk)*64+L)*8+j,
//           value = W[kk*32+(L>>4)*8+j][tile*16+(L&15)]   (tile = h*4+ct)
// battn1/2: B-frag of wal (= W[:,h*64:+64] @ a[h]); col n = which*4+h, n>=8 -> 0
// wheadA  : Wl^T A-frags: idx = ((tile*28+kk)*64+L)*8+j,
//           value = Wl[kk*32+(L>>4)*8+j][tile*16+(L&15)]  (tile 0..1 -> 32 cols)
// ---------------------------------------------------------------------------
__global__ void prep_pack(const float* __restrict__ W1, const float* __restrict__ W2,
                          const float* __restrict__ Wl,
                          const float* __restrict__ as1, const float* __restrict__ ad1,
                          const float* __restrict__ as2, const float* __restrict__ ad2,
                          short* __restrict__ wp1, short* __restrict__ wp2,
                          short* __restrict__ battn1, short* __restrict__ battn2,
                          short* __restrict__ wheadA) {
    int gid = blockIdx.x * 256 + threadIdx.x;
    if (gid < 32768) {
        int j = gid & 7, L = (gid >> 3) & 63, kk = (gid >> 9) & 3, nt = gid >> 11;
        int k = kk * 32 + (L >> 4) * 8 + j, n = nt * 16 + (L & 15);
        wp1[gid] = (short)f2bf(W1[k * 256 + n]);
    } else if (gid < 49152) {
        int g2 = gid - 32768;
        int j = g2 & 7, L = (g2 >> 3) & 63, kk = (g2 >> 9) & 1, nt = g2 >> 10;
        int k = kk * 32 + (L >> 4) * 8 + j, n = nt * 16 + (L & 15);
        wp2[g2] = (short)f2bf(W2[k * 256 + n]);
    } else if (gid < 51200) {
        int g2 = gid - 49152;                 // (kk*64+L)*8+j, kk<4
        int j = g2 & 7, L = (g2 >> 3) & 63, kk = g2 >> 9;
        int n = L & 15, k = kk * 32 + (L >> 4) * 8 + j;
        float val = 0.f;
        if (n < 8) {
            const float* av = ((n >> 2) ? ad1 : as1) + (n & 3) * 64;
            const float* wr = W1 + k * 256 + (n & 3) * 64;
            for (int c = 0; c < 64; ++c) val += wr[c] * av[c];
        }
        battn1[g2] = (short)f2bf(val);
    } else if (gid < 52224) {
        int g2 = gid - 51200;                 // kk<2
        int j = g2 & 7, L = (g2 >> 3) & 63, kk = g2 >> 9;
        int n = L & 15, k = kk * 32 + (L >> 4) * 8 + j;
        float val = 0.f;
        if (n < 8) {
            const float* av = ((n >> 2) ? ad2 : as2) + (n & 3) * 64;
            const float* wr = W2 + k * 256 + (n & 3) * 64;
            for (int c = 0; c < 64; ++c) val += wr[c] * av[c];
        }
        battn2[g2] = (short)f2bf(val);
    } else if (gid < 80896) {
        int g3 = gid - 52224;                 // ((tile*28+kk)*64+L)*8+j
        int j = g3 & 7, L = (g3 >> 3) & 63, rem = g3 >> 9;
        int kk = rem % 28, tile = rem / 28;
        int k = kk * 32 + (L >> 4) * 8 + j, mcol = tile * 16 + (L & 15);
        wheadA[g3] = (short)f2bf(Wl[k * 32 + mcol]);
    }
}

// ---------------------------------------------------------------------------
// One GAT layer, fully in-wave (no barriers).
// a[KK]: A-fragments of the input (held in registers by caller).
// Output written as bf16 pairs into x2b (row stride 36 u32), rows 14/15 = 0.
// ---------------------------------------------------------------------------
template<int KK, bool RELU>
__device__ __forceinline__ void gat_layer(int lane,
    const bf16x8* a, const short* __restrict__ wpB,
    const float* __restrict__ bias,
    const unsigned* cnt, const float* alsd, unsigned* x2b)
{
    const int m = lane & 15, q = lane >> 4;
    f32x4 agg[4];
    #pragma unroll
    for (int ct = 0; ct < 4; ++ct) agg[ct] = f32x4{0.f, 0.f, 0.f, 0.f};

    #pragma unroll
    for (int hp = 0; hp < 2; ++hp) {
        // ---- GEMM tiles for this head pair, converted to bf16 in regs ----
        unsigned hb[8][2];
        #pragma unroll
        for (int hsub = 0; hsub < 2; ++hsub) {
            f32x4 c[4];
            #pragma unroll
            for (int ct = 0; ct < 4; ++ct) c[ct] = f32x4{0.f, 0.f, 0.f, 0.f};
            #pragma unroll
            for (int ct = 0; ct < 4; ++ct)
                #pragma unroll
                for (int kk = 0; kk < KK; ++kk) {
                    bf16x8 b = *(const bf16x8*)(wpB +
                        ((((hp * 2 + hsub) * 4 + ct) * KK + kk) * 64 + lane) * 8);
                    c[ct] = __builtin_amdgcn_mfma_f32_16x16x32_bf16(a[kk], b, c[ct], 0, 0, 0);
                }
            #pragma unroll
            for (int ct = 0; ct < 4; ++ct) {
                hb[hsub * 4 + ct][0] = f2bf(c[ct][0]) | (f2bf(c[ct][1]) << 16);
                hb[hsub * 4 + ct][1] = f2bf(c[ct][2]) | (f2bf(c[ct][3]) << 16);
            }
        }

        // ---- P fragment (B-operand layout): P[d=m][k=q*8+j], k=(head,src) ----
        const int hh = hp * 2 + (q >> 1);
        const float myald = alsd[64 + hh * 16 + m];
        float v[8], s8 = 0.f;
        #pragma unroll
        for (int j = 0; j < 8; ++j) {
            int s = (q & 1) * 8 + j;
            float l = alsd[hh * 16 + s] + myald;
            l = (l > 0.f) ? l : 0.2f * l;
            float e = __expf(l) * (float)cnt[s * 16 + m];
            v[j] = e; s8 += e;
        }
        s8 += __shfl_xor(s8, 16);                 // 16-source sum for (d=m, hh)
        float inv = (s8 > 0.f) ? 0.25f / s8 : 0.f;
        unsigned pb[4];
        #pragma unroll
        for (int j2 = 0; j2 < 4; ++j2)
            pb[j2] = f2bf(v[2 * j2] * inv) | (f2bf(v[2 * j2 + 1] * inv) << 16);
        bf16x8 P = mk8(pb[0], pb[1], pb[2], pb[3]);

        // ---- agg: outT[c][d] += H^T-frag @ P  (H^T frags via shfl from hb) ----
        #pragma unroll
        for (int ct = 0; ct < 4; ++ct) {
            unsigned aw[4];
            #pragma unroll
            for (int jj = 0; jj < 4; ++jj) {
                int srcl = ((q & 1) * 2 + (jj >> 1)) * 16 + m;
                unsigned aE = __shfl((int)hb[ct][jj & 1], srcl);
                unsigned aO = __shfl((int)hb[4 + ct][jj & 1], srcl);
                aw[jj] = (q >> 1) ? aO : aE;
            }
            agg[ct] = __builtin_amdgcn_mfma_f32_16x16x32_bf16(
                mk8(aw[0], aw[1], aw[2], aw[3]), P, agg[ct], 0, 0, 0);
        }
    }

    // ---- bias (+relu), write x2b[d][c] as bf16 pairs; rows d>=14 -> 0 ----
    #pragma unroll
    for (int ct = 0; ct < 4; ++ct) {
        float4 bb = *(const float4*)(bias + ct * 16 + q * 4);
        float o0 = agg[ct][0] + bb.x, o1 = agg[ct][1] + bb.y;
        float o2 = agg[ct][2] + bb.z, o3 = agg[ct][3] + bb.w;
        if (RELU) {
            o0 = fmaxf(o0, 0.f); o1 = fmaxf(o1, 0.f);
            o2 = fmaxf(o2, 0.f); o3 = fmaxf(o3, 0.f);
        }
        if (m >= NN) { o0 = 0.f; o1 = 0.f; o2 = 0.f; o3 = 0.f; }
        unsigned lo = f2bf(o0) | (f2bf(o1) << 16);
        unsigned hi = f2bf(o2) | (f2bf(o3) << 16);
        *(uint2*)(x2b + m * 36 + ct * 8 + q * 2) = make_uint2(lo, hi);
    }
}

// ---------------------------------------------------------------------------
// One wave = one graph. No __syncthreads anywhere.
// ---------------------------------------------------------------------------
__global__ __launch_bounds__(256, 4) void gat_fused(
    const float* __restrict__ feature,   // [B,14,128]
    const int*   __restrict__ edge_list, // [B,182,2] int32
    const float* __restrict__ b1, const float* __restrict__ b2,
    const float* __restrict__ bl, const float* __restrict__ Wpred,
    const float* __restrict__ bp,
    const short* __restrict__ wp1, const short* __restrict__ wp2,
    const short* __restrict__ battn1, const short* __restrict__ battn2,
    const short* __restrict__ wheadA,
    float* __restrict__ out, int B)
{
    const int w = threadIdx.x >> 6, lane = threadIdx.x & 63;
    const int g = blockIdx.x * 4 + w;
    if (g >= B) return;                       // legal: no barriers in kernel
    const int m = lane & 15, q = lane >> 4;

    __shared__ unsigned lds[4 * 960];         // 15360 B: 4 independent wave slabs
    unsigned* cnt  = lds + w * 960;           // [16][16] u32 edge-count matrix
    float*    alsd = (float*)(lds + w * 960 + 256);  // [2][4][16] als/ald
    unsigned* x2b  = lds + w * 960 + 384;     // [16][36] u32 bf16-pair transpose buf

    // ---- cnt: zero, scatter edges + self loops (in-wave DS FIFO ordering) ----
    #pragma unroll
    for (int i = 0; i < 4; ++i) cnt[i * 64 + lane] = 0u;
    const int2* ep = (const int2*)edge_list + (size_t)g * EE;
    #pragma unroll
    for (int r = 0; r < 3; ++r) {
        int i = r * 64 + lane;
        if (i < EE) { int2 e = ep[i]; atomicAdd(&cnt[e.x * 16 + e.y], 1u); }
    }
    if (lane < NN) atomicAdd(&cnt[lane * 17], 1u);

    // ---- layer-1 A-fragments straight from global (f32 -> bf16) ----
    const float* xg = feature + (size_t)g * (NN * FF) + m * FF;
    bf16x8 a1[4];
    #pragma unroll
    for (int kk = 0; kk < 4; ++kk) {
        if (m < NN) {
            float4 v0 = *(const float4*)(xg + kk * 32 + q * 8);
            float4 v1 = *(const float4*)(xg + kk * 32 + q * 8 + 4);
            a1[kk] = mk8(f2bf(v0.x) | (f2bf(v0.y) << 16), f2bf(v0.z) | (f2bf(v0.w) << 16),
                         f2bf(v1.x) | (f2bf(v1.y) << 16), f2bf(v1.z) | (f2bf(v1.w) << 16));
        } else a1[kk] = mk8(0, 0, 0, 0);
    }

    // ---- attn1 via MFMA (cols = which*4+h), write als/ald ----
    {
        f32x4 ca = f32x4{0.f, 0.f, 0.f, 0.f};
        #pragma unroll
        for (int kk = 0; kk < 4; ++kk) {
            bf16x8 b = *(const bf16x8*)(battn1 + (kk * 64 + lane) * 8);
            ca = __builtin_amdgcn_mfma_f32_16x16x32_bf16(a1[kk], b, ca, 0, 0, 0);
        }
        if (m < 8) *(f32x4*)(alsd + (m >> 2) * 64 + (m & 3) * 16 + q * 4) = ca;
    }

    // ---- layer 1: a1 -> x2b (relu) ----
    gat_layer<4, true>(lane, a1, wp1, b1, cnt, alsd, x2b);

    // ---- layer-2 A-fragments from x2b ----
    bf16x8 a2[2];
    #pragma unroll
    for (int kk = 0; kk < 2; ++kk)
        a2[kk] = __builtin_bit_cast(bf16x8, *(const u32x4*)(x2b + m * 36 + kk * 16 + q * 4));

    // ---- attn2 ----
    {
        f32x4 ca = f32x4{0.f, 0.f, 0.f, 0.f};
        #pragma unroll
        for (int kk = 0; kk < 2; ++kk) {
            bf16x8 b = *(const bf16x8*)(battn2 + (kk * 64 + lane) * 8);
            ca = __builtin_amdgcn_mfma_f32_16x16x32_bf16(a2[kk], b, ca, 0, 0, 0);
        }
        if (m < 8) *(f32x4*)(alsd + (m >> 2) * 64 + (m & 3) * 16 + q * 4) = ca;
    }

    // ---- layer 2: a2 -> x2b (overwrites; a2 already in regs) ----
    gat_layer<2, false>(lane, a2, wp2, b2, cnt, alsd, x2b);

    // ---- head: z[0:32] = Wl^T @ x3flat via MFMA (896 = 14*64, no pad rows) ----
    f32x4 z0 = f32x4{0.f, 0.f, 0.f, 0.f}, z1 = f32x4{0.f, 0.f, 0.f, 0.f};
    #pragma unroll 4
    for (int kk = 0; kk < 28; ++kk) {
        bf16x8 bB = __builtin_bit_cast(bf16x8,
            *(const u32x4*)(x2b + (kk >> 1) * 36 + (kk & 1) * 16 + q * 4));  // bcast
        bf16x8 aA0 = *(const bf16x8*)(wheadA + ((0 * 28 + kk) * 64 + lane) * 8);
        bf16x8 aA1 = *(const bf16x8*)(wheadA + ((1 * 28 + kk) * 64 + lane) * 8);
        z0 = __builtin_amdgcn_mfma_f32_16x16x32_bf16(aA0, bB, z0, 0, 0, 0);
        z1 = __builtin_amdgcn_mfma_f32_16x16x32_bf16(aA1, bB, z1, 0, 0, 0);
    }
    // lane(_, q) reg r holds z[tile*16+q*4+r] (duplicated over lane&15)
    float4 bl0 = *(const float4*)(bl + q * 4);
    float4 bl1 = *(const float4*)(bl + 16 + q * 4);
    float4 wq0 = *(const float4*)(Wpred + q * 4);
    float4 wq1 = *(const float4*)(Wpred + 16 + q * 4);
    float p = (z0[0] + bl0.x) * wq0.x + (z0[1] + bl0.y) * wq0.y +
              (z0[2] + bl0.z) * wq0.z + (z0[3] + bl0.w) * wq0.w +
              (z1[0] + bl1.x) * wq1.x + (z1[1] + bl1.y) * wq1.y +
              (z1[2] + bl1.z) * wq1.z + (z1[3] + bl1.w) * wq1.w;
    p += __shfl_xor(p, 16);                   // reduce over q (n-lanes identical)
    p += __shfl_xor(p, 32);
    if (lane == 0) out[g] = 1.f / (1.f + __expf(-(p + bp[0])));
}

extern "C" void kernel_launch(void* const* d_in, const int* in_sizes, int n_in,
                              void* d_out, int out_size, void* d_ws, size_t ws_size,
                              hipStream_t stream) {
    const float* feature = (const float*)d_in[0];
    const int*   edges   = (const int*)d_in[1];
    const float* W1  = (const float*)d_in[2];
    const float* as1 = (const float*)d_in[3];
    const float* ad1 = (const float*)d_in[4];
    const float* b1  = (const float*)d_in[5];
    const float* W2  = (const float*)d_in[6];
    const float* as2 = (const float*)d_in[7];
    const float* ad2 = (const float*)d_in[8];
    const float* b2  = (const float*)d_in[9];
    const float* Wl  = (const float*)d_in[10];
    const float* bl  = (const float*)d_in[11];
    const float* Wp  = (const float*)d_in[12];
    const float* bp  = (const float*)d_in[13];
    float* out = (float*)d_out;

    short* wp1    = (short*)d_ws;            // 32768
    short* wp2    = wp1 + 32768;             // 16384
    short* battn1 = wp2 + 16384;             // 2048
    short* battn2 = battn1 + 2048;           // 1024
    short* wheadA = battn2 + 1024;           // 28672   (total 161792 B)

    prep_pack<<<316, 256, 0, stream>>>(W1, W2, Wl, as1, ad1, as2, ad2,
                                       wp1, wp2, battn1, battn2, wheadA);

    const int B = in_sizes[0] / (NN * FF);
    gat_fused<<<(B + 3) / 4, 256, 0, stream>>>(feature, edges, b1, b2, bl, Wp, bp,
                                               wp1, wp2, battn1, battn2, wheadA,
                                               out, B);
}

// Round 5
// 291.374 us; speedup vs baseline: 6.1236x; 1.0825x over previous
//
#include <hip/hip_runtime.h>

#define NN 14
#define HH 4
#define CC 64
#define FF 128
#define EE 182

typedef __attribute__((ext_vector_type(8))) short bf16x8;
typedef __attribute__((ext_vector_type(4))) float f32x4;
typedef __attribute__((ext_vector_type(4))) unsigned u32x4;

__device__ __forceinline__ unsigned f2bf(float f) {
    unsigned u = __float_as_uint(f);
    return (u + 0x7fffu + ((u >> 16) & 1u)) >> 16;
}
__device__ __forceinline__ bf16x8 mk8(unsigned a, unsigned b, unsigned c, unsigned d) {
    u32x4 u = {a, b, c, d};
    return __builtin_bit_cast(bf16x8, u);
}

// ---------------------------------------------------------------------------
// Weight pre-pack (every launch; d_ws re-poisoned each call).
// wp1/wp2 : W -> MFMA B-frag order: idx = ((tile*KK+kk)*64+L)*8+j,
//           value = W[kk*32+(L>>4)*8+j][tile*16+(L&15)]
// battn1/2: B-frag of (W[:,h*64:+64] @ a[h]); col n = which*4+h, n>=8 -> 0
// wcomb   : Wl @ Wpred (896 floats); wcomb[896] = bl.Wpred + bp
// Layout in d_ws: wp1[32768] wp2[16384] battn1[2048] battn2[1024] | wcomb[897]
// ---------------------------------------------------------------------------
__global__ void prep_pack(const float* __restrict__ W1, const float* __restrict__ W2,
                          const float* __restrict__ Wl, const float* __restrict__ Wpred,
                          const float* __restrict__ bl, const float* __restrict__ bp,
                          const float* __restrict__ as1, const float* __restrict__ ad1,
                          const float* __restrict__ as2, const float* __restrict__ ad2,
                          short* __restrict__ wp1, short* __restrict__ wp2,
                          short* __restrict__ battn1, short* __restrict__ battn2,
                          float* __restrict__ wcomb) {
    int gid = blockIdx.x * 256 + threadIdx.x;
    if (gid < 32768) {
        int j = gid & 7, L = (gid >> 3) & 63, kk = (gid >> 9) & 3, nt = gid >> 11;
        int k = kk * 32 + (L >> 4) * 8 + j, n = nt * 16 + (L & 15);
        wp1[gid] = (short)f2bf(W1[k * 256 + n]);
    } else if (gid < 49152) {
        int g2 = gid - 32768;
        int j = g2 & 7, L = (g2 >> 3) & 63, kk = (g2 >> 9) & 1, nt = g2 >> 10;
        int k = kk * 32 + (L >> 4) * 8 + j, n = nt * 16 + (L & 15);
        wp2[g2] = (short)f2bf(W2[k * 256 + n]);
    } else if (gid < 51200) {
        int g2 = gid - 49152;                 // (kk*64+L)*8+j, kk<4
        int j = g2 & 7, L = (g2 >> 3) & 63, kk = g2 >> 9;
        int n = L & 15, k = kk * 32 + (L >> 4) * 8 + j;
        float val = 0.f;
        if (n < 8) {
            const float* av = ((n >> 2) ? ad1 : as1) + (n & 3) * 64;
            const float* wr = W1 + k * 256 + (n & 3) * 64;
            for (int c = 0; c < 64; ++c) val += wr[c] * av[c];
        }
        battn1[g2] = (short)f2bf(val);
    } else if (gid < 52224) {
        int g2 = gid - 51200;                 // kk<2
        int j = g2 & 7, L = (g2 >> 3) & 63, kk = g2 >> 9;
        int n = L & 15, k = kk * 32 + (L >> 4) * 8 + j;
        float val = 0.f;
        if (n < 8) {
            const float* av = ((n >> 2) ? ad2 : as2) + (n & 3) * 64;
            const float* wr = W2 + k * 256 + (n & 3) * 64;
            for (int c = 0; c < 64; ++c) val += wr[c] * av[c];
        }
        battn2[g2] = (short)f2bf(val);
    } else if (gid < 53120) {
        int i = gid - 52224;                  // wcomb[i] = Wl[i,:] . Wpred
        const float* wr = Wl + i * 32;
        float acc = 0.f;
        #pragma unroll
        for (int j = 0; j < 32; ++j) acc += wr[j] * Wpred[j];
        wcomb[i] = acc;
    } else if (gid == 53120) {
        float acc = bp[0];
        #pragma unroll
        for (int j = 0; j < 32; ++j) acc += bl[j] * Wpred[j];
        wcomb[896] = acc;
    }
}

// ---------------------------------------------------------------------------
// One GAT layer, fully in-wave. a[KK]: A-frags (regs). Result -> o[4] in MFMA
// C-layout: lane(m,q) holds out[node=m][chan=ct*16+q*4+r], bias(+relu) applied,
// rows m>=NN zeroed.
// ---------------------------------------------------------------------------
template<int KK, bool RELU>
__device__ __forceinline__ void gat_layer(int lane,
    const bf16x8* a, const short* wpB,
    const float* __restrict__ bias,
    const unsigned* cnt, const float* alsd, f32x4* o)
{
    const int m = lane & 15, q = lane >> 4;
    f32x4 agg[4];
    #pragma unroll
    for (int ct = 0; ct < 4; ++ct) agg[ct] = f32x4{0.f, 0.f, 0.f, 0.f};

    #pragma unroll
    for (int hp = 0; hp < 2; ++hp) {
        // ---- GEMM tiles for this head pair, converted to bf16 in regs ----
        unsigned hb[8][2];
        #pragma unroll
        for (int hsub = 0; hsub < 2; ++hsub) {
            f32x4 c[4];
            #pragma unroll
            for (int ct = 0; ct < 4; ++ct) c[ct] = f32x4{0.f, 0.f, 0.f, 0.f};
            #pragma unroll
            for (int ct = 0; ct < 4; ++ct)
                #pragma unroll
                for (int kk = 0; kk < KK; ++kk) {
                    bf16x8 b = *(const bf16x8*)(wpB +
                        ((((hp * 2 + hsub) * 4 + ct) * KK + kk) * 64 + lane) * 8);
                    c[ct] = __builtin_amdgcn_mfma_f32_16x16x32_bf16(a[kk], b, c[ct], 0, 0, 0);
                }
            #pragma unroll
            for (int ct = 0; ct < 4; ++ct) {
                hb[hsub * 4 + ct][0] = f2bf(c[ct][0]) | (f2bf(c[ct][1]) << 16);
                hb[hsub * 4 + ct][1] = f2bf(c[ct][2]) | (f2bf(c[ct][3]) << 16);
            }
        }

        // ---- P fragment (B-layout): P[d=m][k=q*8+j], k=(head,src) ----
        const int hh = hp * 2 + (q >> 1);
        const float myald = alsd[64 + hh * 16 + m];
        float v[8], s8 = 0.f;
        #pragma unroll
        for (int j = 0; j < 8; ++j) {
            int s = (q & 1) * 8 + j;
            float l = alsd[hh * 16 + s] + myald;
            l = (l > 0.f) ? l : 0.2f * l;
            float e = __expf(l) * (float)cnt[s * 16 + m];
            v[j] = e; s8 += e;
        }
        s8 += __shfl_xor(s8, 16);
        float inv = (s8 > 0.f) ? 0.25f / s8 : 0.f;
        unsigned pb[4];
        #pragma unroll
        for (int j2 = 0; j2 < 4; ++j2)
            pb[j2] = f2bf(v[2 * j2] * inv) | (f2bf(v[2 * j2 + 1] * inv) << 16);
        bf16x8 P = mk8(pb[0], pb[1], pb[2], pb[3]);

        // ---- agg: outT[c][d] += H^T-frag @ P  (H^T frags via shfl) ----
        #pragma unroll
        for (int ct = 0; ct < 4; ++ct) {
            unsigned aw[4];
            #pragma unroll
            for (int jj = 0; jj < 4; ++jj) {
                int srcl = ((q & 1) * 2 + (jj >> 1)) * 16 + m;
                unsigned aE = __shfl((int)hb[ct][jj & 1], srcl);
                unsigned aO = __shfl((int)hb[4 + ct][jj & 1], srcl);
                aw[jj] = (q >> 1) ? aO : aE;
            }
            agg[ct] = __builtin_amdgcn_mfma_f32_16x16x32_bf16(
                mk8(aw[0], aw[1], aw[2], aw[3]), P, agg[ct], 0, 0, 0);
        }
    }

    // ---- bias (+relu), zero pad rows ----
    #pragma unroll
    for (int ct = 0; ct < 4; ++ct) {
        float4 bb = *(const float4*)(bias + ct * 16 + q * 4);
        float o0 = agg[ct][0] + bb.x, o1 = agg[ct][1] + bb.y;
        float o2 = agg[ct][2] + bb.z, o3 = agg[ct][3] + bb.w;
        if (RELU) {
            o0 = fmaxf(o0, 0.f); o1 = fmaxf(o1, 0.f);
            o2 = fmaxf(o2, 0.f); o3 = fmaxf(o3, 0.f);
        }
        if (m >= NN) { o0 = 0.f; o1 = 0.f; o2 = 0.f; o3 = 0.f; }
        o[ct] = f32x4{o0, o1, o2, o3};
    }
}

// ---------------------------------------------------------------------------
// One wave = one graph; 8 waves/block; one barrier (weight staging) only.
// ---------------------------------------------------------------------------
__global__ __launch_bounds__(512, 6) void gat_fused(
    const float* __restrict__ feature,   // [B,14,128]
    const int*   __restrict__ edge_list, // [B,182,2] int32
    const float* __restrict__ b1, const float* __restrict__ b2,
    const short* __restrict__ wp1,       // W1 B-frags (streamed from L2)
    const short* __restrict__ wpck,      // wp2|battn1|battn2 contiguous (19456 sh)
    const float* __restrict__ wcomb,     // [897]
    float* __restrict__ out, int B)
{
    const int w = threadIdx.x >> 6, lane = threadIdx.x & 63;
    const int g = blockIdx.x * 8 + w;
    const int m = lane & 15, q = lane >> 4;

    __shared__ __align__(16) short swts[19456];      // 38912 B staged weights
    __shared__ unsigned slab[8 * 384];               // 12288 B: cnt(256)+alsd(128)/wave

    // ---- cooperative weight staging (the only __syncthreads) ----
    {
        const u32x4* srcw = (const u32x4*)wpck;
        u32x4* dstw = (u32x4*)swts;
        #pragma unroll
        for (int r = 0; r < 5; ++r) {
            int i = r * 512 + threadIdx.x;
            if (i < 2432) dstw[i] = srcw[i];
        }
    }
    __syncthreads();
    if (g >= B) return;

    const short* swp2  = swts;
    const short* sbat1 = swts + 16384;
    const short* sbat2 = swts + 18432;
    unsigned* cnt  = slab + w * 384;
    float*    alsd = (float*)(slab + w * 384 + 256);

    // ---- cnt: zero, scatter edges + self loops (in-wave DS ordering) ----
    #pragma unroll
    for (int i = 0; i < 4; ++i) cnt[i * 64 + lane] = 0u;
    const int2* ep = (const int2*)edge_list + (size_t)g * EE;
    #pragma unroll
    for (int r = 0; r < 3; ++r) {
        int i = r * 64 + lane;
        if (i < EE) { int2 e = ep[i]; atomicAdd(&cnt[e.x * 16 + e.y], 1u); }
    }
    if (lane < NN) atomicAdd(&cnt[lane * 17], 1u);

    // ---- layer-1 A-fragments from global (f32 -> bf16) ----
    const float* xg = feature + (size_t)g * (NN * FF) + m * FF;
    bf16x8 a1[4];
    #pragma unroll
    for (int kk = 0; kk < 4; ++kk) {
        if (m < NN) {
            float4 v0 = *(const float4*)(xg + kk * 32 + q * 8);
            float4 v1 = *(const float4*)(xg + kk * 32 + q * 8 + 4);
            a1[kk] = mk8(f2bf(v0.x) | (f2bf(v0.y) << 16), f2bf(v0.z) | (f2bf(v0.w) << 16),
                         f2bf(v1.x) | (f2bf(v1.y) << 16), f2bf(v1.z) | (f2bf(v1.w) << 16));
        } else a1[kk] = mk8(0, 0, 0, 0);
    }

    // ---- attn1 via MFMA (B staged in LDS) ----
    {
        f32x4 ca = f32x4{0.f, 0.f, 0.f, 0.f};
        #pragma unroll
        for (int kk = 0; kk < 4; ++kk) {
            bf16x8 b = *(const bf16x8*)(sbat1 + (kk * 64 + lane) * 8);
            ca = __builtin_amdgcn_mfma_f32_16x16x32_bf16(a1[kk], b, ca, 0, 0, 0);
        }
        if (m < 8) *(f32x4*)(alsd + (m >> 2) * 64 + (m & 3) * 16 + q * 4) = ca;
    }

    // ---- layer 1 (relu) ----
    f32x4 o1[4];
    gat_layer<4, true>(lane, a1, wp1, b1, cnt, alsd, o1);

    // ---- layer2 A-frags via pack + shfl (no LDS round-trip) ----
    unsigned p1[4][2];
    #pragma unroll
    for (int ct = 0; ct < 4; ++ct) {
        p1[ct][0] = f2bf(o1[ct][0]) | (f2bf(o1[ct][1]) << 16);
        p1[ct][1] = f2bf(o1[ct][2]) | (f2bf(o1[ct][3]) << 16);
    }
    bf16x8 a2[2];
    #pragma unroll
    for (int kk = 0; kk < 2; ++kk) {
        unsigned wv[4];
        #pragma unroll
        for (int j2 = 0; j2 < 4; ++j2) {
            int srcl = ((q & 1) * 2 + (j2 >> 1)) * 16 + m;
            unsigned vE = __shfl((int)p1[2 * kk][j2 & 1], srcl);
            unsigned vO = __shfl((int)p1[2 * kk + 1][j2 & 1], srcl);
            wv[j2] = (q >> 1) ? vO : vE;
        }
        a2[kk] = mk8(wv[0], wv[1], wv[2], wv[3]);
    }

    // ---- attn2 ----
    {
        f32x4 ca = f32x4{0.f, 0.f, 0.f, 0.f};
        #pragma unroll
        for (int kk = 0; kk < 2; ++kk) {
            bf16x8 b = *(const bf16x8*)(sbat2 + (kk * 64 + lane) * 8);
            ca = __builtin_amdgcn_mfma_f32_16x16x32_bf16(a2[kk], b, ca, 0, 0, 0);
        }
        if (m < 8) *(f32x4*)(alsd + (m >> 2) * 64 + (m & 3) * 16 + q * 4) = ca;
    }

    // ---- layer 2 (B staged in LDS) ----
    f32x4 o2[4];
    gat_layer<2, false>(lane, a2, swp2, b2, cnt, alsd, o2);

    // ---- composite head: p = x3 . wcomb + c0 ; sigmoid ----
    float p = 0.f;
    if (m < NN) {
        const float* wc = wcomb + m * 64 + q * 4;
        #pragma unroll
        for (int ct = 0; ct < 4; ++ct) {
            float4 w4 = *(const float4*)(wc + ct * 16);
            p += o2[ct][0] * w4.x + o2[ct][1] * w4.y +
                 o2[ct][2] * w4.z + o2[ct][3] * w4.w;
        }
    }
    p += __shfl_xor(p, 1);  p += __shfl_xor(p, 2);  p += __shfl_xor(p, 4);
    p += __shfl_xor(p, 8);  p += __shfl_xor(p, 16); p += __shfl_xor(p, 32);
    if (lane == 0) out[g] = 1.f / (1.f + __expf(-(p + wcomb[896])));
}

extern "C" void kernel_launch(void* const* d_in, const int* in_sizes, int n_in,
                              void* d_out, int out_size, void* d_ws, size_t ws_size,
                              hipStream_t stream) {
    const float* feature = (const float*)d_in[0];
    const int*   edges   = (const int*)d_in[1];
    const float* W1  = (const float*)d_in[2];
    const float* as1 = (const float*)d_in[3];
    const float* ad1 = (const float*)d_in[4];
    const float* b1  = (const float*)d_in[5];
    const float* W2  = (const float*)d_in[6];
    const float* as2 = (const float*)d_in[7];
    const float* ad2 = (const float*)d_in[8];
    const float* b2  = (const float*)d_in[9];
    const float* Wl  = (const float*)d_in[10];
    const float* bl  = (const float*)d_in[11];
    const float* Wp  = (const float*)d_in[12];
    const float* bp  = (const float*)d_in[13];
    float* out = (float*)d_out;

    short* wp1    = (short*)d_ws;            // 32768 sh
    short* wp2    = wp1 + 32768;             // 16384 sh
    short* battn1 = wp2 + 16384;             // 2048 sh
    short* battn2 = battn1 + 2048;           // 1024 sh   (wp2..battn2 contiguous)
    float* wcomb  = (float*)(battn2 + 1024); // 897 f32 (16B-aligned: 104448 B offset)

    prep_pack<<<208, 256, 0, stream>>>(W1, W2, Wl, Wp, bl, bp, as1, ad1, as2, ad2,
                                       wp1, wp2, battn1, battn2, wcomb);

    const int B = in_sizes[0] / (NN * FF);
    gat_fused<<<(B + 7) / 8, 512, 0, stream>>>(feature, edges, b1, b2,
                                               wp1, wp2, wcomb, out, B);
}

// Round 6
// 286.212 us; speedup vs baseline: 6.2341x; 1.0180x over previous
//
#include <hip/hip_runtime.h>

#define NN 14
#define HH 4
#define CC 64
#define FF 128
#define EE 182

typedef __attribute__((ext_vector_type(8))) short bf16x8;
typedef __attribute__((ext_vector_type(4))) float f32x4;
typedef __attribute__((ext_vector_type(4))) unsigned u32x4;

__device__ __forceinline__ unsigned f2bf(float f) {
    unsigned u = __float_as_uint(f);
    return (u + 0x7fffu + ((u >> 16) & 1u)) >> 16;
}
__device__ __forceinline__ bf16x8 mk8(unsigned a, unsigned b, unsigned c, unsigned d) {
    u32x4 u = {a, b, c, d};
    return __builtin_bit_cast(bf16x8, u);
}

// ---------------------------------------------------------------------------
// Weight pre-pack (every launch; d_ws re-poisoned each call).
// wp1/wp2 : W -> MFMA B-frag order: idx = ((tile*KK+kk)*64+L)*8+j,
//           value = W[kk*32+(L>>4)*8+j][tile*16+(L&15)]
// battn1/2: B-frag of (W[:,h*64:+64] @ a[h]); col n = which*4+h, n>=8 -> 0
// wcomb   : Wl @ Wpred (896 floats); wcomb[896] = bl.Wpred + bp
// ---------------------------------------------------------------------------
__global__ void prep_pack(const float* __restrict__ W1, const float* __restrict__ W2,
                          const float* __restrict__ Wl, const float* __restrict__ Wpred,
                          const float* __restrict__ bl, const float* __restrict__ bp,
                          const float* __restrict__ as1, const float* __restrict__ ad1,
                          const float* __restrict__ as2, const float* __restrict__ ad2,
                          short* __restrict__ wp1, short* __restrict__ wp2,
                          short* __restrict__ battn1, short* __restrict__ battn2,
                          float* __restrict__ wcomb) {
    int gid = blockIdx.x * 256 + threadIdx.x;
    if (gid < 32768) {
        int j = gid & 7, L = (gid >> 3) & 63, kk = (gid >> 9) & 3, nt = gid >> 11;
        int k = kk * 32 + (L >> 4) * 8 + j, n = nt * 16 + (L & 15);
        wp1[gid] = (short)f2bf(W1[k * 256 + n]);
    } else if (gid < 49152) {
        int g2 = gid - 32768;
        int j = g2 & 7, L = (g2 >> 3) & 63, kk = (g2 >> 9) & 1, nt = g2 >> 10;
        int k = kk * 32 + (L >> 4) * 8 + j, n = nt * 16 + (L & 15);
        wp2[g2] = (short)f2bf(W2[k * 256 + n]);
    } else if (gid < 51200) {
        int g2 = gid - 49152;                 // (kk*64+L)*8+j, kk<4
        int j = g2 & 7, L = (g2 >> 3) & 63, kk = g2 >> 9;
        int n = L & 15, k = kk * 32 + (L >> 4) * 8 + j;
        float val = 0.f;
        if (n < 8) {
            const float* av = ((n >> 2) ? ad1 : as1) + (n & 3) * 64;
            const float* wr = W1 + k * 256 + (n & 3) * 64;
            for (int c = 0; c < 64; ++c) val += wr[c] * av[c];
        }
        battn1[g2] = (short)f2bf(val);
    } else if (gid < 52224) {
        int g2 = gid - 51200;                 // kk<2
        int j = g2 & 7, L = (g2 >> 3) & 63, kk = g2 >> 9;
        int n = L & 15, k = kk * 32 + (L >> 4) * 8 + j;
        float val = 0.f;
        if (n < 8) {
            const float* av = ((n >> 2) ? ad2 : as2) + (n & 3) * 64;
            const float* wr = W2 + k * 256 + (n & 3) * 64;
            for (int c = 0; c < 64; ++c) val += wr[c] * av[c];
        }
        battn2[g2] = (short)f2bf(val);
    } else if (gid < 53120) {
        int i = gid - 52224;                  // wcomb[i] = Wl[i,:] . Wpred
        const float* wr = Wl + i * 32;
        float acc = 0.f;
        #pragma unroll
        for (int j = 0; j < 32; ++j) acc += wr[j] * Wpred[j];
        wcomb[i] = acc;
    } else if (gid == 53120) {
        float acc = bp[0];
        #pragma unroll
        for (int j = 0; j < 32; ++j) acc += bl[j] * Wpred[j];
        wcomb[896] = acc;
    }
}

// ---------------------------------------------------------------------------
// One GAT layer, fully in-wave. a[KK]: A-frags (regs).
// RELU path (layer 1): packs bias+relu'd output straight to bf16 pairs po[4][2]
//   (pad rows zeroed) -- minimizes live registers.
// non-RELU path (layer 2): f32 C-layout result in o[4].
// ---------------------------------------------------------------------------
template<int KK, bool RELU>
__device__ __forceinline__ void gat_layer(int lane,
    const bf16x8* a, const short* wpB,
    const float* __restrict__ bias,
    const unsigned* cnt, const float* alsd,
    f32x4* o, unsigned (*po)[2])
{
    const int m = lane & 15, q = lane >> 4;
    f32x4 agg[4];
    #pragma unroll
    for (int ct = 0; ct < 4; ++ct) agg[ct] = f32x4{0.f, 0.f, 0.f, 0.f};

    #pragma unroll
    for (int hp = 0; hp < 2; ++hp) {
        // ---- GEMM tiles for this head pair, converted to bf16 in regs ----
        unsigned hb[8][2];
        #pragma unroll
        for (int hsub = 0; hsub < 2; ++hsub) {
            f32x4 c[4];
            #pragma unroll
            for (int ct = 0; ct < 4; ++ct) c[ct] = f32x4{0.f, 0.f, 0.f, 0.f};
            #pragma unroll
            for (int ct = 0; ct < 4; ++ct)
                #pragma unroll
                for (int kk = 0; kk < KK; ++kk) {
                    bf16x8 b = *(const bf16x8*)(wpB +
                        ((((hp * 2 + hsub) * 4 + ct) * KK + kk) * 64 + lane) * 8);
                    c[ct] = __builtin_amdgcn_mfma_f32_16x16x32_bf16(a[kk], b, c[ct], 0, 0, 0);
                }
            #pragma unroll
            for (int ct = 0; ct < 4; ++ct) {
                hb[hsub * 4 + ct][0] = f2bf(c[ct][0]) | (f2bf(c[ct][1]) << 16);
                hb[hsub * 4 + ct][1] = f2bf(c[ct][2]) | (f2bf(c[ct][3]) << 16);
            }
        }

        // ---- P fragment (B-layout): P[d=m][k=q*8+j], k=(head,src) ----
        const int hh = hp * 2 + (q >> 1);
        const float myald = alsd[64 + hh * 16 + m];
        float v[8], s8 = 0.f;
        #pragma unroll
        for (int j = 0; j < 8; ++j) {
            int s = (q & 1) * 8 + j;
            float l = alsd[hh * 16 + s] + myald;
            l = (l > 0.f) ? l : 0.2f * l;
            float e = __expf(l) * (float)cnt[s * 16 + m];
            v[j] = e; s8 += e;
        }
        s8 += __shfl_xor(s8, 16);
        float inv = (s8 > 0.f) ? 0.25f / s8 : 0.f;
        unsigned pb[4];
        #pragma unroll
        for (int j2 = 0; j2 < 4; ++j2)
            pb[j2] = f2bf(v[2 * j2] * inv) | (f2bf(v[2 * j2 + 1] * inv) << 16);
        bf16x8 P = mk8(pb[0], pb[1], pb[2], pb[3]);

        // ---- agg: outT[c][d] += H^T-frag @ P  (H^T frags via shfl) ----
        #pragma unroll
        for (int ct = 0; ct < 4; ++ct) {
            unsigned aw[4];
            #pragma unroll
            for (int jj = 0; jj < 4; ++jj) {
                int srcl = ((q & 1) * 2 + (jj >> 1)) * 16 + m;
                unsigned aE = __shfl((int)hb[ct][jj & 1], srcl);
                unsigned aO = __shfl((int)hb[4 + ct][jj & 1], srcl);
                aw[jj] = (q >> 1) ? aO : aE;
            }
            agg[ct] = __builtin_amdgcn_mfma_f32_16x16x32_bf16(
                mk8(aw[0], aw[1], aw[2], aw[3]), P, agg[ct], 0, 0, 0);
        }
    }

    // ---- epilogue: bias (+relu) ----
    #pragma unroll
    for (int ct = 0; ct < 4; ++ct) {
        float4 bb = *(const float4*)(bias + ct * 16 + q * 4);
        float o0 = agg[ct][0] + bb.x, o1 = agg[ct][1] + bb.y;
        float o2 = agg[ct][2] + bb.z, o3 = agg[ct][3] + bb.w;
        if (RELU) {
            o0 = fmaxf(o0, 0.f); o1 = fmaxf(o1, 0.f);
            o2 = fmaxf(o2, 0.f); o3 = fmaxf(o3, 0.f);
            if (m >= NN) { o0 = 0.f; o1 = 0.f; o2 = 0.f; o3 = 0.f; }
            po[ct][0] = f2bf(o0) | (f2bf(o1) << 16);
            po[ct][1] = f2bf(o2) | (f2bf(o3) << 16);
        } else {
            o[ct] = f32x4{o0, o1, o2, o3};
        }
    }
}

// ---------------------------------------------------------------------------
// One wave = one graph; 8 waves/block; one barrier (weight staging) only.
// __launch_bounds__(512,4): 128-VGPR budget -- (512,6) forced an 85-reg cap
// and ~100 MB of scratch spill traffic (R5 post-mortem).
// ---------------------------------------------------------------------------
__global__ __launch_bounds__(512, 4) void gat_fused(
    const float* __restrict__ feature,   // [B,14,128]
    const int*   __restrict__ edge_list, // [B,182,2] int32
    const float* __restrict__ b1, const float* __restrict__ b2,
    const short* __restrict__ wp1,       // W1 B-frags (streamed from L2)
    const short* __restrict__ wpck,      // wp2|battn1|battn2 contiguous (19456 sh)
    const float* __restrict__ wcomb,     // [897]
    float* __restrict__ out, int B)
{
    const int w = threadIdx.x >> 6, lane = threadIdx.x & 63;
    const int g = blockIdx.x * 8 + w;
    const int m = lane & 15, q = lane >> 4;

    __shared__ __align__(16) short swts[19456];      // 38912 B staged weights
    __shared__ unsigned slab[8 * 384];               // 12288 B: cnt(256)+alsd(128)/wave

    // ---- cooperative weight staging (the only __syncthreads) ----
    {
        const u32x4* srcw = (const u32x4*)wpck;
        u32x4* dstw = (u32x4*)swts;
        #pragma unroll
        for (int r = 0; r < 5; ++r) {
            int i = r * 512 + threadIdx.x;
            if (i < 2432) dstw[i] = srcw[i];
        }
    }
    __syncthreads();
    if (g >= B) return;

    const short* swp2  = swts;
    const short* sbat1 = swts + 16384;
    const short* sbat2 = swts + 18432;
    unsigned* cnt  = slab + w * 384;
    float*    alsd = (float*)(slab + w * 384 + 256);

    // ---- cnt: zero, scatter edges + self loops (in-wave DS ordering) ----
    #pragma unroll
    for (int i = 0; i < 4; ++i) cnt[i * 64 + lane] = 0u;
    const int2* ep = (const int2*)edge_list + (size_t)g * EE;
    #pragma unroll
    for (int r = 0; r < 3; ++r) {
        int i = r * 64 + lane;
        if (i < EE) { int2 e = ep[i]; atomicAdd(&cnt[e.x * 16 + e.y], 1u); }
    }
    if (lane < NN) atomicAdd(&cnt[lane * 17], 1u);

    // ---- layer-1 A-fragments from global (f32 -> bf16) ----
    const float* xg = feature + (size_t)g * (NN * FF) + m * FF;
    bf16x8 a1[4];
    #pragma unroll
    for (int kk = 0; kk < 4; ++kk) {
        if (m < NN) {
            float4 v0 = *(const float4*)(xg + kk * 32 + q * 8);
            float4 v1 = *(const float4*)(xg + kk * 32 + q * 8 + 4);
            a1[kk] = mk8(f2bf(v0.x) | (f2bf(v0.y) << 16), f2bf(v0.z) | (f2bf(v0.w) << 16),
                         f2bf(v1.x) | (f2bf(v1.y) << 16), f2bf(v1.z) | (f2bf(v1.w) << 16));
        } else a1[kk] = mk8(0, 0, 0, 0);
    }

    // ---- attn1 via MFMA (B staged in LDS) ----
    {
        f32x4 ca = f32x4{0.f, 0.f, 0.f, 0.f};
        #pragma unroll
        for (int kk = 0; kk < 4; ++kk) {
            bf16x8 b = *(const bf16x8*)(sbat1 + (kk * 64 + lane) * 8);
            ca = __builtin_amdgcn_mfma_f32_16x16x32_bf16(a1[kk], b, ca, 0, 0, 0);
        }
        if (m < 8) *(f32x4*)(alsd + (m >> 2) * 64 + (m & 3) * 16 + q * 4) = ca;
    }

    // ---- layer 1 (relu) -> packed bf16 pairs po1 ----
    unsigned po1[4][2];
    gat_layer<4, true>(lane, a1, wp1, b1, cnt, alsd, nullptr, po1);

    // ---- layer2 A-frags via shfl transpose of po1 (no LDS round-trip) ----
    bf16x8 a2[2];
    #pragma unroll
    for (int kk = 0; kk < 2; ++kk) {
        unsigned wv[4];
        #pragma unroll
        for (int j2 = 0; j2 < 4; ++j2) {
            int srcl = ((q & 1) * 2 + (j2 >> 1)) * 16 + m;
            unsigned vE = __shfl((int)po1[2 * kk][j2 & 1], srcl);
            unsigned vO = __shfl((int)po1[2 * kk + 1][j2 & 1], srcl);
            wv[j2] = (q >> 1) ? vO : vE;
        }
        a2[kk] = mk8(wv[0], wv[1], wv[2], wv[3]);
    }

    // ---- attn2 ----
    {
        f32x4 ca = f32x4{0.f, 0.f, 0.f, 0.f};
        #pragma unroll
        for (int kk = 0; kk < 2; ++kk) {
            bf16x8 b = *(const bf16x8*)(sbat2 + (kk * 64 + lane) * 8);
            ca = __builtin_amdgcn_mfma_f32_16x16x32_bf16(a2[kk], b, ca, 0, 0, 0);
        }
        if (m < 8) *(f32x4*)(alsd + (m >> 2) * 64 + (m & 3) * 16 + q * 4) = ca;
    }

    // ---- layer 2 (B staged in LDS) -> f32 o2 ----
    f32x4 o2[4];
    gat_layer<2, false>(lane, a2, swp2, b2, cnt, alsd, o2, nullptr);

    // ---- composite head: p = x3 . wcomb + c0 ; sigmoid ----
    float p = 0.f;
    if (m < NN) {
        const float* wc = wcomb + m * 64 + q * 4;
        #pragma unroll
        for (int ct = 0; ct < 4; ++ct) {
            float4 w4 = *(const float4*)(wc + ct * 16);
            p += o2[ct][0] * w4.x + o2[ct][1] * w4.y +
                 o2[ct][2] * w4.z + o2[ct][3] * w4.w;
        }
    }
    p += __shfl_xor(p, 1);  p += __shfl_xor(p, 2);  p += __shfl_xor(p, 4);
    p += __shfl_xor(p, 8);  p += __shfl_xor(p, 16); p += __shfl_xor(p, 32);
    if (lane == 0) out[g] = 1.f / (1.f + __expf(-(p + wcomb[896])));
}

extern "C" void kernel_launch(void* const* d_in, const int* in_sizes, int n_in,
                              void* d_out, int out_size, void* d_ws, size_t ws_size,
                              hipStream_t stream) {
    const float* feature = (const float*)d_in[0];
    const int*   edges   = (const int*)d_in[1];
    const float* W1  = (const float*)d_in[2];
    const float* as1 = (const float*)d_in[3];
    const float* ad1 = (const float*)d_in[4];
    const float* b1  = (const float*)d_in[5];
    const float* W2  = (const float*)d_in[6];
    const float* as2 = (const float*)d_in[7];
    const float* ad2 = (const float*)d_in[8];
    const float* b2  = (const float*)d_in[9];
    const float* Wl  = (const float*)d_in[10];
    const float* bl  = (const float*)d_in[11];
    const float* Wp  = (const float*)d_in[12];
    const float* bp  = (const float*)d_in[13];
    float* out = (float*)d_out;

    short* wp1    = (short*)d_ws;            // 32768 sh
    short* wp2    = wp1 + 32768;             // 16384 sh
    short* battn1 = wp2 + 16384;             // 2048 sh
    short* battn2 = battn1 + 2048;           // 1024 sh   (wp2..battn2 contiguous)
    float* wcomb  = (float*)(battn2 + 1024); // 897 f32

    prep_pack<<<208, 256, 0, stream>>>(W1, W2, Wl, Wp, bl, bp, as1, ad1, as2, ad2,
                                       wp1, wp2, battn1, battn2, wcomb);

    const int B = in_sizes[0] / (NN * FF);
    gat_fused<<<(B + 7) / 8, 512, 0, stream>>>(feature, edges, b1, b2,
                                               wp1, wp2, wcomb, out, B);
}

// Round 7
// 281.423 us; speedup vs baseline: 6.3402x; 1.0170x over previous
//
#include <hip/hip_runtime.h>

#define NN 14
#define HH 4
#define CC 64
#define FF 128
#define EE 182

typedef __attribute__((ext_vector_type(8))) short bf16x8;
typedef __attribute__((ext_vector_type(4))) float f32x4;
typedef __attribute__((ext_vector_type(4))) unsigned u32x4;

__device__ __forceinline__ unsigned f2bf(float f) {            // RNE (prep only)
    unsigned u = __float_as_uint(f);
    return (u + 0x7fffu + ((u >> 16) & 1u)) >> 16;
}
// pack two f32 -> bf16 pair (round-half-away): add,add,v_perm = 3 VALU
__device__ __forceinline__ unsigned pack2bf(float lo, float hi) {
    return __builtin_amdgcn_perm(__float_as_uint(hi) + 0x8000u,
                                 __float_as_uint(lo) + 0x8000u, 0x07060302u);
}
__device__ __forceinline__ bf16x8 mk8(unsigned a, unsigned b, unsigned c, unsigned d) {
    u32x4 u = {a, b, c, d};
    return __builtin_bit_cast(bf16x8, u);
}

// ---------------------------------------------------------------------------
// Weight pre-pack (every launch; d_ws re-poisoned each call).
// wp1/wp2 : W -> MFMA B-frag order: idx = ((tile*KK+kk)*64+L)*8+j,
//           value = W[kk*32+(L>>4)*8+j][tile*16+(L&15)]
// battn1/2: B-frag of (W[:,h*64:+64] @ a[h]); col n = which*4+h, n>=8 -> 0
// wcomb   : Wl @ Wpred (896 floats); wcomb[896] = bl.Wpred + bp
// ---------------------------------------------------------------------------
__global__ void prep_pack(const float* __restrict__ W1, const float* __restrict__ W2,
                          const float* __restrict__ Wl, const float* __restrict__ Wpred,
                          const float* __restrict__ bl, const float* __restrict__ bp,
                          const float* __restrict__ as1, const float* __restrict__ ad1,
                          const float* __restrict__ as2, const float* __restrict__ ad2,
                          short* __restrict__ wp1, short* __restrict__ wp2,
                          short* __restrict__ battn1, short* __restrict__ battn2,
                          float* __restrict__ wcomb) {
    int gid = blockIdx.x * 256 + threadIdx.x;
    if (gid < 32768) {
        int j = gid & 7, L = (gid >> 3) & 63, kk = (gid >> 9) & 3, nt = gid >> 11;
        int k = kk * 32 + (L >> 4) * 8 + j, n = nt * 16 + (L & 15);
        wp1[gid] = (short)f2bf(W1[k * 256 + n]);
    } else if (gid < 49152) {
        int g2 = gid - 32768;
        int j = g2 & 7, L = (g2 >> 3) & 63, kk = (g2 >> 9) & 1, nt = g2 >> 10;
        int k = kk * 32 + (L >> 4) * 8 + j, n = nt * 16 + (L & 15);
        wp2[g2] = (short)f2bf(W2[k * 256 + n]);
    } else if (gid < 51200) {
        int g2 = gid - 49152;                 // (kk*64+L)*8+j, kk<4
        int j = g2 & 7, L = (g2 >> 3) & 63, kk = g2 >> 9;
        int n = L & 15, k = kk * 32 + (L >> 4) * 8 + j;
        float val = 0.f;
        if (n < 8) {
            const float* av = ((n >> 2) ? ad1 : as1) + (n & 3) * 64;
            const float* wr = W1 + k * 256 + (n & 3) * 64;
            for (int c = 0; c < 64; ++c) val += wr[c] * av[c];
        }
        battn1[g2] = (short)f2bf(val);
    } else if (gid < 52224) {
        int g2 = gid - 51200;                 // kk<2
        int j = g2 & 7, L = (g2 >> 3) & 63, kk = g2 >> 9;
        int n = L & 15, k = kk * 32 + (L >> 4) * 8 + j;
        float val = 0.f;
        if (n < 8) {
            const float* av = ((n >> 2) ? ad2 : as2) + (n & 3) * 64;
            const float* wr = W2 + k * 256 + (n & 3) * 64;
            for (int c = 0; c < 64; ++c) val += wr[c] * av[c];
        }
        battn2[g2] = (short)f2bf(val);
    } else if (gid < 53120) {
        int i = gid - 52224;                  // wcomb[i] = Wl[i,:] . Wpred
        const float* wr = Wl + i * 32;
        float acc = 0.f;
        #pragma unroll
        for (int j = 0; j < 32; ++j) acc += wr[j] * Wpred[j];
        wcomb[i] = acc;
    } else if (gid == 53120) {
        float acc = bp[0];
        #pragma unroll
        for (int j = 0; j < 32; ++j) acc += bl[j] * Wpred[j];
        wcomb[896] = acc;
    }
}

// ---------------------------------------------------------------------------
// One GAT layer, fully in-wave. a[KK]: A-frags (regs).
// cntf: [16 dst][20] float edge counts (transposed, padded). alsd: [2][4][16].
// RELU path packs output straight to bf16 pairs po[4][2]; else f32 o[4].
// ---------------------------------------------------------------------------
template<int KK, bool RELU>
__device__ __forceinline__ void gat_layer(int lane,
    const bf16x8* a, const short* wpB,
    const float* __restrict__ bias,
    const float* cntf, const float* alsd,
    f32x4* o, unsigned (*po)[2])
{
    const int m = lane & 15, q = lane >> 4;
    f32x4 agg[4];
    #pragma unroll
    for (int ct = 0; ct < 4; ++ct) agg[ct] = f32x4{0.f, 0.f, 0.f, 0.f};

    #pragma unroll
    for (int hp = 0; hp < 2; ++hp) {
        // ---- GEMM tiles for this head pair, packed to bf16 pairs in regs ----
        unsigned hb[8][2];
        #pragma unroll
        for (int hsub = 0; hsub < 2; ++hsub) {
            f32x4 c[4];
            #pragma unroll
            for (int ct = 0; ct < 4; ++ct) c[ct] = f32x4{0.f, 0.f, 0.f, 0.f};
            #pragma unroll
            for (int ct = 0; ct < 4; ++ct)
                #pragma unroll
                for (int kk = 0; kk < KK; ++kk) {
                    bf16x8 b = *(const bf16x8*)(wpB +
                        ((((hp * 2 + hsub) * 4 + ct) * KK + kk) * 64 + lane) * 8);
                    c[ct] = __builtin_amdgcn_mfma_f32_16x16x32_bf16(a[kk], b, c[ct], 0, 0, 0);
                }
            #pragma unroll
            for (int ct = 0; ct < 4; ++ct) {
                hb[hsub * 4 + ct][0] = pack2bf(c[ct][0], c[ct][1]);
                hb[hsub * 4 + ct][1] = pack2bf(c[ct][2], c[ct][3]);
            }
        }

        // ---- P fragment (B-layout): P[d=m][k=q*8+j], k=(head,src) ----
        const int hh = hp * 2 + (q >> 1);
        const float myald = alsd[64 + hh * 16 + m];
        const float* asrc = alsd + hh * 16 + (q & 1) * 8;
        const float* csrc = cntf + m * 20 + (q & 1) * 8;
        f32x4 aL = *(const f32x4*)asrc, aH = *(const f32x4*)(asrc + 4);
        f32x4 cL = *(const f32x4*)csrc, cH = *(const f32x4*)(csrc + 4);
        float v[8], s8 = 0.f;
        #pragma unroll
        for (int j = 0; j < 8; ++j) {
            float l = ((j < 4) ? aL[j] : aH[j - 4]) + myald;
            l = fmaxf(l, 0.f) + 0.2f * fminf(l, 0.f);     // leaky, branch-free
            float e = __expf(l) * ((j < 4) ? cL[j] : cH[j - 4]);
            v[j] = e; s8 += e;
        }
        s8 += __shfl_xor(s8, 16);
        float inv = (s8 > 0.f) ? 0.25f / s8 : 0.f;
        bf16x8 P = mk8(pack2bf(v[0] * inv, v[1] * inv), pack2bf(v[2] * inv, v[3] * inv),
                       pack2bf(v[4] * inv, v[5] * inv), pack2bf(v[6] * inv, v[7] * inv));

        // ---- agg: outT[c][d] += H^T-frag @ P  (H^T frags via shfl) ----
        #pragma unroll
        for (int ct = 0; ct < 4; ++ct) {
            unsigned aw[4];
            #pragma unroll
            for (int jj = 0; jj < 4; ++jj) {
                int srcl = ((q & 1) * 2 + (jj >> 1)) * 16 + m;
                unsigned aE = __shfl((int)hb[ct][jj & 1], srcl);
                unsigned aO = __shfl((int)hb[4 + ct][jj & 1], srcl);
                aw[jj] = (q >> 1) ? aO : aE;
            }
            agg[ct] = __builtin_amdgcn_mfma_f32_16x16x32_bf16(
                mk8(aw[0], aw[1], aw[2], aw[3]), P, agg[ct], 0, 0, 0);
        }
    }

    // ---- epilogue: bias (+relu) ----
    #pragma unroll
    for (int ct = 0; ct < 4; ++ct) {
        float4 bb = *(const float4*)(bias + ct * 16 + q * 4);
        float o0 = agg[ct][0] + bb.x, o1 = agg[ct][1] + bb.y;
        float o2 = agg[ct][2] + bb.z, o3 = agg[ct][3] + bb.w;
        if (RELU) {
            o0 = fmaxf(o0, 0.f); o1 = fmaxf(o1, 0.f);
            o2 = fmaxf(o2, 0.f); o3 = fmaxf(o3, 0.f);
            if (m >= NN) { o0 = 0.f; o1 = 0.f; o2 = 0.f; o3 = 0.f; }
            po[ct][0] = pack2bf(o0, o1);
            po[ct][1] = pack2bf(o2, o3);
        } else {
            o[ct] = f32x4{o0, o1, o2, o3};
        }
    }
}

// ---------------------------------------------------------------------------
// One wave = one graph; 8 waves/block; one barrier (weight staging) only.
// (512,4): 128-VGPR budget -- (512,6)'s 85-reg cap caused ~100 MB spill (R5).
// ---------------------------------------------------------------------------
__global__ __launch_bounds__(512, 4) void gat_fused(
    const float* __restrict__ feature,   // [B,14,128]
    const int*   __restrict__ edge_list, // [B,182,2] int32
    const float* __restrict__ b1, const float* __restrict__ b2,
    const short* __restrict__ wp1,       // W1 B-frags (streamed from L2)
    const short* __restrict__ wpck,      // wp2|battn1|battn2 contiguous (19456 sh)
    const float* __restrict__ wcomb,     // [897]
    float* __restrict__ out, int B)
{
    const int w = threadIdx.x >> 6, lane = threadIdx.x & 63;
    const int g = blockIdx.x * 8 + w;
    const int m = lane & 15, q = lane >> 4;

    __shared__ __align__(16) short swts[19456];      // 38912 B staged weights
    __shared__ __align__(16) unsigned slab[8 * 448]; // 14336 B: cntf(320)+alsd(128)/wave

    float* cntf = (float*)(slab + w * 448);          // [16][20] float counts
    float* alsd = (float*)(slab + w * 448 + 320);    // [2][4][16]

    const bool live = (g < B);

    // ---- issue weight staging loads (consumed after barrier) ----
    const u32x4* srcw = (const u32x4*)wpck;
    u32x4* dstw = (u32x4*)swts;
    #pragma unroll
    for (int r = 0; r < 5; ++r) {
        int i = r * 512 + threadIdx.x;
        if (i < 2432) dstw[i] = srcw[i];
    }

    // ---- pre-barrier (independent of swts): cnt scatter + feature -> a1 ----
    #pragma unroll
    for (int i = 0; i < 5; ++i) cntf[i * 64 + lane] = 0.f;
    if (live) {
        const int2* ep = (const int2*)edge_list + (size_t)g * EE;
        #pragma unroll
        for (int r = 0; r < 3; ++r) {
            int i = r * 64 + lane;
            if (i < EE) { int2 e = ep[i]; atomicAdd(&cntf[e.y * 20 + e.x], 1.f); }
        }
        if (lane < NN) atomicAdd(&cntf[lane * 21], 1.f);
    }

    bf16x8 a1[4];
    #pragma unroll
    for (int kk = 0; kk < 4; ++kk) a1[kk] = mk8(0, 0, 0, 0);
    if (live && m < NN) {
        const float* xg = feature + (size_t)g * (NN * FF) + m * FF;
        #pragma unroll
        for (int kk = 0; kk < 4; ++kk) {
            float4 v0 = *(const float4*)(xg + kk * 32 + q * 8);
            float4 v1 = *(const float4*)(xg + kk * 32 + q * 8 + 4);
            a1[kk] = mk8(pack2bf(v0.x, v0.y), pack2bf(v0.z, v0.w),
                         pack2bf(v1.x, v1.y), pack2bf(v1.z, v1.w));
        }
    }

    __syncthreads();
    if (!live) return;

    const short* swp2  = swts;
    const short* sbat1 = swts + 16384;
    const short* sbat2 = swts + 18432;

    // ---- attn1 via MFMA (B staged in LDS) ----
    {
        f32x4 ca = f32x4{0.f, 0.f, 0.f, 0.f};
        #pragma unroll
        for (int kk = 0; kk < 4; ++kk) {
            bf16x8 b = *(const bf16x8*)(sbat1 + (kk * 64 + lane) * 8);
            ca = __builtin_amdgcn_mfma_f32_16x16x32_bf16(a1[kk], b, ca, 0, 0, 0);
        }
        if (m < 8) *(f32x4*)(alsd + (m >> 2) * 64 + (m & 3) * 16 + q * 4) = ca;
    }

    // ---- layer 1 (relu) -> packed bf16 pairs po1 ----
    unsigned po1[4][2];
    gat_layer<4, true>(lane, a1, wp1, b1, cntf, alsd, nullptr, po1);

    // ---- layer2 A-frags via shfl transpose of po1 ----
    bf16x8 a2[2];
    #pragma unroll
    for (int kk = 0; kk < 2; ++kk) {
        unsigned wv[4];
        #pragma unroll
        for (int j2 = 0; j2 < 4; ++j2) {
            int srcl = ((q & 1) * 2 + (j2 >> 1)) * 16 + m;
            unsigned vE = __shfl((int)po1[2 * kk][j2 & 1], srcl);
            unsigned vO = __shfl((int)po1[2 * kk + 1][j2 & 1], srcl);
            wv[j2] = (q >> 1) ? vO : vE;
        }
        a2[kk] = mk8(wv[0], wv[1], wv[2], wv[3]);
    }

    // ---- attn2 ----
    {
        f32x4 ca = f32x4{0.f, 0.f, 0.f, 0.f};
        #pragma unroll
        for (int kk = 0; kk < 2; ++kk) {
            bf16x8 b = *(const bf16x8*)(sbat2 + (kk * 64 + lane) * 8);
            ca = __builtin_amdgcn_mfma_f32_16x16x32_bf16(a2[kk], b, ca, 0, 0, 0);
        }
        if (m < 8) *(f32x4*)(alsd + (m >> 2) * 64 + (m & 3) * 16 + q * 4) = ca;
    }

    // ---- layer 2 (B staged in LDS) -> f32 o2 ----
    f32x4 o2[4];
    gat_layer<2, false>(lane, a2, swp2, b2, cntf, alsd, o2, nullptr);

    // ---- composite head: p = x3 . wcomb + c0 ; sigmoid ----
    float p = 0.f;
    if (m < NN) {
        const float* wc = wcomb + m * 64 + q * 4;
        #pragma unroll
        for (int ct = 0; ct < 4; ++ct) {
            float4 w4 = *(const float4*)(wc + ct * 16);
            p += o2[ct][0] * w4.x + o2[ct][1] * w4.y +
                 o2[ct][2] * w4.z + o2[ct][3] * w4.w;
        }
    }
    p += __shfl_xor(p, 1);  p += __shfl_xor(p, 2);  p += __shfl_xor(p, 4);
    p += __shfl_xor(p, 8);  p += __shfl_xor(p, 16); p += __shfl_xor(p, 32);
    if (lane == 0) out[g] = 1.f / (1.f + __expf(-(p + wcomb[896])));
}

extern "C" void kernel_launch(void* const* d_in, const int* in_sizes, int n_in,
                              void* d_out, int out_size, void* d_ws, size_t ws_size,
                              hipStream_t stream) {
    const float* feature = (const float*)d_in[0];
    const int*   edges   = (const int*)d_in[1];
    const float* W1  = (const float*)d_in[2];
    const float* as1 = (const float*)d_in[3];
    const float* ad1 = (const float*)d_in[4];
    const float* b1  = (const float*)d_in[5];
    const float* W2  = (const float*)d_in[6];
    const float* as2 = (const float*)d_in[7];
    const float* ad2 = (const float*)d_in[8];
    const float* b2  = (const float*)d_in[9];
    const float* Wl  = (const float*)d_in[10];
    const float* bl  = (const float*)d_in[11];
    const float* Wp  = (const float*)d_in[12];
    const float* bp  = (const float*)d_in[13];
    float* out = (float*)d_out;

    short* wp1    = (short*)d_ws;            // 32768 sh
    short* wp2    = wp1 + 32768;             // 16384 sh
    short* battn1 = wp2 + 16384;             // 2048 sh
    short* battn2 = battn1 + 2048;           // 1024 sh   (wp2..battn2 contiguous)
    float* wcomb  = (float*)(battn2 + 1024); // 897 f32

    prep_pack<<<208, 256, 0, stream>>>(W1, W2, Wl, Wp, bl, bp, as1, ad1, as2, ad2,
                                       wp1, wp2, battn1, battn2, wcomb);

    const int B = in_sizes[0] / (NN * FF);
    gat_fused<<<(B + 7) / 8, 512, 0, stream>>>(feature, edges, b1, b2,
                                               wp1, wp2, wcomb, out, B);
}

// Round 8
// 240.263 us; speedup vs baseline: 7.4263x; 1.1713x over previous
//
#include <hip/hip_runtime.h>

#define NN 14
#define HH 4
#define CC 64
#define FF 128
#define EE 182

typedef __attribute__((ext_vector_type(8))) short bf16x8;
typedef __attribute__((ext_vector_type(4))) float f32x4;
typedef __attribute__((ext_vector_type(4))) unsigned u32x4;

__device__ __forceinline__ unsigned f2bf(float f) {            // RNE (prep only)
    unsigned u = __float_as_uint(f);
    return (u + 0x7fffu + ((u >> 16) & 1u)) >> 16;
}
// pack two f32 -> bf16 pair (round-half-away): add,add,v_perm = 3 VALU
__device__ __forceinline__ unsigned pack2bf(float lo, float hi) {
    return __builtin_amdgcn_perm(__float_as_uint(hi) + 0x8000u,
                                 __float_as_uint(lo) + 0x8000u, 0x07060302u);
}
__device__ __forceinline__ bf16x8 mk8(unsigned a, unsigned b, unsigned c, unsigned d) {
    u32x4 u = {a, b, c, d};
    return __builtin_bit_cast(bf16x8, u);
}

// ---------------------------------------------------------------------------
// Weight pre-pack (every launch; d_ws re-poisoned each call).
// wp1/wp2 : W -> MFMA B-frag order: idx = ((tile*KK+kk)*64+L)*8+j,
//           value = W[kk*32+(L>>4)*8+j][tile*16+(L&15)]
// battn1/2: B-frag of (W[:,h*64:+64] @ a[h]); col n = which*4+h, n>=8 -> 0
// wcomb   : Wl @ Wpred (896 floats); wcomb[896] = bl.Wpred + bp
// ---------------------------------------------------------------------------
__global__ void prep_pack(const float* __restrict__ W1, const float* __restrict__ W2,
                          const float* __restrict__ Wl, const float* __restrict__ Wpred,
                          const float* __restrict__ bl, const float* __restrict__ bp,
                          const float* __restrict__ as1, const float* __restrict__ ad1,
                          const float* __restrict__ as2, const float* __restrict__ ad2,
                          short* __restrict__ wp1, short* __restrict__ wp2,
                          short* __restrict__ battn1, short* __restrict__ battn2,
                          float* __restrict__ wcomb) {
    int gid = blockIdx.x * 256 + threadIdx.x;
    if (gid < 32768) {
        int j = gid & 7, L = (gid >> 3) & 63, kk = (gid >> 9) & 3, nt = gid >> 11;
        int k = kk * 32 + (L >> 4) * 8 + j, n = nt * 16 + (L & 15);
        wp1[gid] = (short)f2bf(W1[k * 256 + n]);
    } else if (gid < 49152) {
        int g2 = gid - 32768;
        int j = g2 & 7, L = (g2 >> 3) & 63, kk = (g2 >> 9) & 1, nt = g2 >> 10;
        int k = kk * 32 + (L >> 4) * 8 + j, n = nt * 16 + (L & 15);
        wp2[g2] = (short)f2bf(W2[k * 256 + n]);
    } else if (gid < 51200) {
        int g2 = gid - 49152;                 // (kk*64+L)*8+j, kk<4
        int j = g2 & 7, L = (g2 >> 3) & 63, kk = g2 >> 9;
        int n = L & 15, k = kk * 32 + (L >> 4) * 8 + j;
        float val = 0.f;
        if (n < 8) {
            const float* av = ((n >> 2) ? ad1 : as1) + (n & 3) * 64;
            const float* wr = W1 + k * 256 + (n & 3) * 64;
            for (int c = 0; c < 64; ++c) val += wr[c] * av[c];
        }
        battn1[g2] = (short)f2bf(val);
    } else if (gid < 52224) {
        int g2 = gid - 51200;                 // kk<2
        int j = g2 & 7, L = (g2 >> 3) & 63, kk = g2 >> 9;
        int n = L & 15, k = kk * 32 + (L >> 4) * 8 + j;
        float val = 0.f;
        if (n < 8) {
            const float* av = ((n >> 2) ? ad2 : as2) + (n & 3) * 64;
            const float* wr = W2 + k * 256 + (n & 3) * 64;
            for (int c = 0; c < 64; ++c) val += wr[c] * av[c];
        }
        battn2[g2] = (short)f2bf(val);
    } else if (gid < 53120) {
        int i = gid - 52224;                  // wcomb[i] = Wl[i,:] . Wpred
        const float* wr = Wl + i * 32;
        float acc = 0.f;
        #pragma unroll
        for (int j = 0; j < 32; ++j) acc += wr[j] * Wpred[j];
        wcomb[i] = acc;
    } else if (gid == 53120) {
        float acc = bp[0];
        #pragma unroll
        for (int j = 0; j < 32; ++j) acc += bl[j] * Wpred[j];
        wcomb[896] = acc;
    }
}

// ---------------------------------------------------------------------------
// One GAT layer, fully in-wave. a[KK]: A-frags (regs). wpB: LDS B-frags.
// cntf: [16 dst][20] float edge counts (transposed). alsd: [2][4][16].
// RELU path packs output straight to bf16 pairs po[4][2]; else f32 o[4].
// ---------------------------------------------------------------------------
template<int KK, bool RELU>
__device__ __forceinline__ void gat_layer(int lane,
    const bf16x8* a, const short* wpB,
    const float* __restrict__ bias,
    const float* cntf, const float* alsd,
    f32x4* o, unsigned (*po)[2])
{
    const int m = lane & 15, q = lane >> 4;
    f32x4 agg[4];
    #pragma unroll
    for (int ct = 0; ct < 4; ++ct) agg[ct] = f32x4{0.f, 0.f, 0.f, 0.f};

    #pragma unroll
    for (int hp = 0; hp < 2; ++hp) {
        // ---- GEMM tiles for this head pair, packed to bf16 pairs in regs ----
        unsigned hb[8][2];
        #pragma unroll
        for (int hsub = 0; hsub < 2; ++hsub) {
            f32x4 c[4];
            #pragma unroll
            for (int ct = 0; ct < 4; ++ct) c[ct] = f32x4{0.f, 0.f, 0.f, 0.f};
            #pragma unroll
            for (int ct = 0; ct < 4; ++ct)
                #pragma unroll
                for (int kk = 0; kk < KK; ++kk) {
                    bf16x8 b = *(const bf16x8*)(wpB +
                        ((((hp * 2 + hsub) * 4 + ct) * KK + kk) * 64 + lane) * 8);
                    c[ct] = __builtin_amdgcn_mfma_f32_16x16x32_bf16(a[kk], b, c[ct], 0, 0, 0);
                }
            #pragma unroll
            for (int ct = 0; ct < 4; ++ct) {
                hb[hsub * 4 + ct][0] = pack2bf(c[ct][0], c[ct][1]);
                hb[hsub * 4 + ct][1] = pack2bf(c[ct][2], c[ct][3]);
            }
        }

        // ---- P fragment (B-layout): P[d=m][k=q*8+j], k=(head,src) ----
        const int hh = hp * 2 + (q >> 1);
        const float myald = alsd[64 + hh * 16 + m];
        const float* asrc = alsd + hh * 16 + (q & 1) * 8;
        const float* csrc = cntf + m * 20 + (q & 1) * 8;
        f32x4 aL = *(const f32x4*)asrc, aH = *(const f32x4*)(asrc + 4);
        f32x4 cL = *(const f32x4*)csrc, cH = *(const f32x4*)(csrc + 4);
        float v[8], s8 = 0.f;
        #pragma unroll
        for (int j = 0; j < 8; ++j) {
            float l = ((j < 4) ? aL[j] : aH[j - 4]) + myald;
            l = fmaxf(l, 0.f) + 0.2f * fminf(l, 0.f);     // leaky, branch-free
            float e = __expf(l) * ((j < 4) ? cL[j] : cH[j - 4]);
            v[j] = e; s8 += e;
        }
        s8 += __shfl_xor(s8, 16);
        float inv = (s8 > 0.f) ? 0.25f / s8 : 0.f;
        bf16x8 P = mk8(pack2bf(v[0] * inv, v[1] * inv), pack2bf(v[2] * inv, v[3] * inv),
                       pack2bf(v[4] * inv, v[5] * inv), pack2bf(v[6] * inv, v[7] * inv));

        // ---- agg: outT[c][d] += H^T-frag @ P  (H^T frags via shfl) ----
        #pragma unroll
        for (int ct = 0; ct < 4; ++ct) {
            unsigned aw[4];
            #pragma unroll
            for (int jj = 0; jj < 4; ++jj) {
                int srcl = ((q & 1) * 2 + (jj >> 1)) * 16 + m;
                unsigned aE = __shfl((int)hb[ct][jj & 1], srcl);
                unsigned aO = __shfl((int)hb[4 + ct][jj & 1], srcl);
                aw[jj] = (q >> 1) ? aO : aE;
            }
            agg[ct] = __builtin_amdgcn_mfma_f32_16x16x32_bf16(
                mk8(aw[0], aw[1], aw[2], aw[3]), P, agg[ct], 0, 0, 0);
        }
    }

    // ---- epilogue: bias (+relu) ----
    #pragma unroll
    for (int ct = 0; ct < 4; ++ct) {
        float4 bb = *(const float4*)(bias + ct * 16 + q * 4);
        float o0 = agg[ct][0] + bb.x, o1 = agg[ct][1] + bb.y;
        float o2 = agg[ct][2] + bb.z, o3 = agg[ct][3] + bb.w;
        if (RELU) {
            o0 = fmaxf(o0, 0.f); o1 = fmaxf(o1, 0.f);
            o2 = fmaxf(o2, 0.f); o3 = fmaxf(o3, 0.f);
            if (m >= NN) { o0 = 0.f; o1 = 0.f; o2 = 0.f; o3 = 0.f; }
            po[ct][0] = pack2bf(o0, o1);
            po[ct][1] = pack2bf(o2, o3);
        } else {
            o[ct] = f32x4{o0, o1, o2, o3};
        }
    }
}

// ---------------------------------------------------------------------------
// Persistent blocks: 1024 thr (16 waves), 1 block/CU (130 KB LDS), each wave
// processes 4 consecutive graphs. ALL weights staged in LDS once; one barrier.
// (1024,4): 128-VGPR budget (spill cliff is below ~85, R5).
// ---------------------------------------------------------------------------
__global__ __launch_bounds__(1024, 4) void gat_fused(
    const float* __restrict__ feature,   // [B,14,128]
    const int*   __restrict__ edge_list, // [B,182,2] int32
    const float* __restrict__ b1, const float* __restrict__ b2,
    const short* __restrict__ wpck,      // wp1|wp2|battn1|battn2 (52224 shorts)
    const float* __restrict__ wcomb,     // [897]
    float* __restrict__ out, int B)
{
    const int w = threadIdx.x >> 6, lane = threadIdx.x & 63;
    const int m = lane & 15, q = lane >> 4;

    __shared__ __align__(16) short swts[52224];      // 104448 B: all packed weights
    __shared__ __align__(16) unsigned slab[16 * 448]; // 28672 B: cntf(320)+alsd(128)/wave

    float* cntf = (float*)(slab + w * 448);          // [16][20] float counts
    float* alsd = (float*)(slab + w * 448 + 320);    // [2][4][16]

    // ---- stage ALL packed weights into LDS (once per persistent block) ----
    {
        const u32x4* srcw = (const u32x4*)wpck;
        u32x4* dstw = (u32x4*)swts;
        #pragma unroll
        for (int r = 0; r < 7; ++r) {
            int i = r * 1024 + (int)threadIdx.x;
            if (i < 6528) dstw[i] = srcw[i];          // 104448 B
        }
    }
    __syncthreads();                                  // the only barrier

    const short* swp1  = swts;
    const short* swp2  = swts + 32768;
    const short* sbat1 = swts + 49152;
    const short* sbat2 = swts + 51200;

    const int g0 = blockIdx.x * 64 + w * 4;

    #pragma clang loop unroll(disable)
    for (int it = 0; it < 4; ++it) {
        const int g = g0 + it;
        if (g >= B) break;

        // ---- cnt: zero + scatter edges + self loops (in-wave DS ordering) ----
        #pragma unroll
        for (int i = 0; i < 5; ++i) cntf[i * 64 + lane] = 0.f;
        {
            const int2* ep = (const int2*)edge_list + (size_t)g * EE;
            #pragma unroll
            for (int r = 0; r < 3; ++r) {
                int i = r * 64 + lane;
                if (i < EE) { int2 e = ep[i]; atomicAdd(&cntf[e.y * 20 + e.x], 1.f); }
            }
            if (lane < NN) atomicAdd(&cntf[lane * 21], 1.f);
        }

        // ---- layer-1 A-fragments from global (f32 -> bf16) ----
        bf16x8 a1[4];
        #pragma unroll
        for (int kk = 0; kk < 4; ++kk) a1[kk] = mk8(0, 0, 0, 0);
        if (m < NN) {
            const float* xg = feature + (size_t)g * (NN * FF) + m * FF;
            #pragma unroll
            for (int kk = 0; kk < 4; ++kk) {
                float4 v0 = *(const float4*)(xg + kk * 32 + q * 8);
                float4 v1 = *(const float4*)(xg + kk * 32 + q * 8 + 4);
                a1[kk] = mk8(pack2bf(v0.x, v0.y), pack2bf(v0.z, v0.w),
                             pack2bf(v1.x, v1.y), pack2bf(v1.z, v1.w));
            }
        }

        // ---- attn1 via MFMA (B staged in LDS) ----
        {
            f32x4 ca = f32x4{0.f, 0.f, 0.f, 0.f};
            #pragma unroll
            for (int kk = 0; kk < 4; ++kk) {
                bf16x8 b = *(const bf16x8*)(sbat1 + (kk * 64 + lane) * 8);
                ca = __builtin_amdgcn_mfma_f32_16x16x32_bf16(a1[kk], b, ca, 0, 0, 0);
            }
            if (m < 8) *(f32x4*)(alsd + (m >> 2) * 64 + (m & 3) * 16 + q * 4) = ca;
        }

        // ---- layer 1 (relu) -> packed bf16 pairs po1 ----
        unsigned po1[4][2];
        gat_layer<4, true>(lane, a1, swp1, b1, cntf, alsd, nullptr, po1);

        // ---- layer2 A-frags via shfl transpose of po1 ----
        bf16x8 a2[2];
        #pragma unroll
        for (int kk = 0; kk < 2; ++kk) {
            unsigned wv[4];
            #pragma unroll
            for (int j2 = 0; j2 < 4; ++j2) {
                int srcl = ((q & 1) * 2 + (j2 >> 1)) * 16 + m;
                unsigned vE = __shfl((int)po1[2 * kk][j2 & 1], srcl);
                unsigned vO = __shfl((int)po1[2 * kk + 1][j2 & 1], srcl);
                wv[j2] = (q >> 1) ? vO : vE;
            }
            a2[kk] = mk8(wv[0], wv[1], wv[2], wv[3]);
        }

        // ---- attn2 ----
        {
            f32x4 ca = f32x4{0.f, 0.f, 0.f, 0.f};
            #pragma unroll
            for (int kk = 0; kk < 2; ++kk) {
                bf16x8 b = *(const bf16x8*)(sbat2 + (kk * 64 + lane) * 8);
                ca = __builtin_amdgcn_mfma_f32_16x16x32_bf16(a2[kk], b, ca, 0, 0, 0);
            }
            if (m < 8) *(f32x4*)(alsd + (m >> 2) * 64 + (m & 3) * 16 + q * 4) = ca;
        }

        // ---- layer 2 (B staged in LDS) -> f32 o2 ----
        f32x4 o2[4];
        gat_layer<2, false>(lane, a2, swp2, b2, cntf, alsd, o2, nullptr);

        // ---- composite head: p = x3 . wcomb + c0 ; sigmoid ----
        float p = 0.f;
        if (m < NN) {
            const float* wc = wcomb + m * 64 + q * 4;
            #pragma unroll
            for (int ct = 0; ct < 4; ++ct) {
                float4 w4 = *(const float4*)(wc + ct * 16);
                p += o2[ct][0] * w4.x + o2[ct][1] * w4.y +
                     o2[ct][2] * w4.z + o2[ct][3] * w4.w;
            }
        }
        p += __shfl_xor(p, 1);  p += __shfl_xor(p, 2);  p += __shfl_xor(p, 4);
        p += __shfl_xor(p, 8);  p += __shfl_xor(p, 16); p += __shfl_xor(p, 32);
        if (lane == 0) out[g] = 1.f / (1.f + __expf(-(p + wcomb[896])));
    }
}

extern "C" void kernel_launch(void* const* d_in, const int* in_sizes, int n_in,
                              void* d_out, int out_size, void* d_ws, size_t ws_size,
                              hipStream_t stream) {
    const float* feature = (const float*)d_in[0];
    const int*   edges   = (const int*)d_in[1];
    const float* W1  = (const float*)d_in[2];
    const float* as1 = (const float*)d_in[3];
    const float* ad1 = (const float*)d_in[4];
    const float* b1  = (const float*)d_in[5];
    const float* W2  = (const float*)d_in[6];
    const float* as2 = (const float*)d_in[7];
    const float* ad2 = (const float*)d_in[8];
    const float* b2  = (const float*)d_in[9];
    const float* Wl  = (const float*)d_in[10];
    const float* bl  = (const float*)d_in[11];
    const float* Wp  = (const float*)d_in[12];
    const float* bp  = (const float*)d_in[13];
    float* out = (float*)d_out;

    short* wp1    = (short*)d_ws;            // 32768 sh
    short* wp2    = wp1 + 32768;             // 16384 sh
    short* battn1 = wp2 + 16384;             // 2048 sh
    short* battn2 = battn1 + 2048;           // 1024 sh  (wp1..battn2 contiguous)
    float* wcomb  = (float*)(battn2 + 1024); // 897 f32

    prep_pack<<<208, 256, 0, stream>>>(W1, W2, Wl, Wp, bl, bp, as1, ad1, as2, ad2,
                                       wp1, wp2, battn1, battn2, wcomb);

    const int B = in_sizes[0] / (NN * FF);
    gat_fused<<<(B + 63) / 64, 1024, 0, stream>>>(feature, edges, b1, b2,
                                                  wp1, wcomb, out, B);
}